// Round 4
// baseline (1531.129 us; speedup 1.0000x reference)
//
#include <hip/hip_runtime.h>

typedef unsigned long long ull;

// Problem constants: N=100000 nodes, E=3200000 edges, F=128, C=32, H=24
//
// Pipeline:
//   1. build_runs:  8192 edges/block counting-sorted by bucket (dst>>8) fully
//                   inside LDS; coalesced write of the bucket-grouped run +
//                   runoff[r][b] segment table.
//   2. gemm_dual_a: h_a = x@K1a, p_a = x@K2a + ba
//   3. fused_gather_x1:  per bucket b: LDS agg[256][32]; stream the bucket's
//                   segments from every run, agg[dloc][ch] += w*h[src][ch]
//                   via LDS f32 atomics (bank = ch -> 2-way, free);
//                   x1 = relu(agg + p_a) written coalesced.
//   4. gemm_dual_b: h_b = x1@K1b, p_b = x1@K2b + bb
//   5. fused_gather_pool: same accumulate; block-reduce relu(agg+p_b) into
//                   pooled (32 global atomics/block).
//   6. dense epilogue
//
// etmp record: low = src | (dst&255)<<20 ; high = f32 bits of w  (src < 2^20)

#define CHUNK 8192
#define NPB   256
#define NBMAX 512

// ---------------------------------------------------------------------------
// Phase 1: LDS-staged counting sort of each 8192-edge chunk by bucket.
// ---------------------------------------------------------------------------
__global__ __launch_bounds__(512) void build_runs_kernel(
    const int* __restrict__ src, const int* __restrict__ dst,
    const float* __restrict__ w,
    ull* __restrict__ etmp, int* __restrict__ runoff,
    int e, int nruns, int nb)
{
    __shared__ ull stage[CHUNK];      // 64 KB
    __shared__ int hist[NBMAX];       // counts, then cursor
    __shared__ int scn[NBMAX];
    const int r = blockIdx.x, tid = threadIdx.x;
    const int base = r * CHUNK;
    const int cnt = min(CHUNK, e - base);

    hist[tid] = 0;
    __syncthreads();

    int dreg[CHUNK / 512];
    #pragma unroll
    for (int k = 0; k < CHUNK / 512; ++k) {
        int i = tid + k * 512;
        int d = (i < cnt) ? dst[base + i] : -1;
        dreg[k] = d;
        if (d >= 0) atomicAdd(&hist[d >> 8], 1);
    }
    __syncthreads();

    // exclusive scan over NBMAX entries (512 threads, 1 apiece)
    int v = hist[tid];
    scn[tid] = v;
    __syncthreads();
    for (int off = 1; off < NBMAX; off <<= 1) {
        int u = (tid >= off) ? scn[tid - off] : 0;
        __syncthreads();
        scn[tid] += u;
        __syncthreads();
    }
    const int ex = scn[tid] - v;      // exclusive prefix
    hist[tid] = ex;                   // becomes cursor
    // segment table: runoff[r][b] = global start of (run r, bucket b), b<=nb.
    // ex at tid==nb equals cnt (all dst buckets < nb), giving the sentinel.
    if (tid <= nb) runoff[(size_t)r * (nb + 1) + tid] = base + ex;
    __syncthreads();

    // scatter into LDS stage
    #pragma unroll
    for (int k = 0; k < CHUNK / 512; ++k) {
        int i = tid + k * 512;
        int d = dreg[k];
        if (d >= 0) {
            int pos = atomicAdd(&hist[d >> 8], 1);
            unsigned lo = (unsigned)src[base + i] | ((unsigned)(d & 255) << 20);
            stage[pos] = (ull)lo | ((ull)__float_as_uint(w[base + i]) << 32);
        }
    }
    __syncthreads();

    // coalesced copy-out
    for (int i = tid; i < cnt; i += 512) etmp[base + i] = stage[i];
}

// ---------------------------------------------------------------------------
// Fused bucket gather: agg[dloc][ch] += w * h[src][ch] over the bucket's
// segments in every run. 32 lanes per edge (one channel each) -> LDS bank
// = ch, 2 lanes/bank per wave op (free). 8 waves stream 8 runs in parallel.
// ---------------------------------------------------------------------------
__device__ __forceinline__ void bucket_accumulate(
    float* agg, const ull* __restrict__ etmp, const int* __restrict__ runoff,
    const float* __restrict__ h, int b, int nruns, int nb)
{
    const int tid = threadIdx.x;
    for (int i = tid; i < NPB * 32; i += 512) agg[i] = 0.f;
    __syncthreads();

    const int wid = tid >> 6;        // wave 0..7
    const int se  = (tid >> 5) & 1;  // sub-edge within wave (2 edges/wave-iter)
    const int ch  = tid & 31;

    for (int r = wid; r < nruns; r += 8) {
        const int s0 = runoff[(size_t)r * (nb + 1) + b];
        const int s1 = runoff[(size_t)r * (nb + 1) + b + 1];
        for (int i = s0 + se; i < s1; i += 2) {
            ull pk = etmp[i];
            int s20  = (int)(pk & 0xFFFFFu);
            int dloc = (int)((pk >> 20) & 255u);
            float wv = __uint_as_float((unsigned)(pk >> 32));
            float hv = h[(size_t)s20 * 32 + ch];
            atomicAdd(&agg[dloc * 32 + ch], wv * hv);
        }
    }
    __syncthreads();
}

__global__ __launch_bounds__(512) void fused_gather_x1(
    const ull* __restrict__ etmp, const int* __restrict__ runoff,
    const float* __restrict__ h, const float* __restrict__ p,
    float* __restrict__ x1, int n, int nruns, int nb)
{
    __shared__ float agg[NPB * 32];  // 32 KB
    const int b = blockIdx.x;
    bucket_accumulate(agg, etmp, runoff, h, b, nruns, nb);

    const int node0 = b * NPB;
    for (int i = threadIdx.x; i < NPB * 32; i += 512) {
        int node = node0 + (i >> 5);
        if (node < n) {
            size_t g = (size_t)node * 32 + (i & 31);
            x1[g] = fmaxf(agg[i] + p[g], 0.f);
        }
    }
}

__global__ __launch_bounds__(512) void fused_gather_pool(
    const ull* __restrict__ etmp, const int* __restrict__ runoff,
    const float* __restrict__ h, const float* __restrict__ p,
    float* __restrict__ pooled, int n, int nruns, int nb)
{
    __shared__ float agg[NPB * 32];
    const int b = blockIdx.x;
    bucket_accumulate(agg, etmp, runoff, h, b, nruns, nb);

    const int node0 = b * NPB;
    float acc = 0.f;   // accumulates channel (tid & 31)
    for (int i = threadIdx.x; i < NPB * 32; i += 512) {
        int node = node0 + (i >> 5);
        if (node < n) {
            size_t g = (size_t)node * 32 + (i & 31);
            acc += fmaxf(agg[i] + p[g], 0.f);
        }
    }
    __syncthreads();
    agg[threadIdx.x] = acc;
    __syncthreads();
    if (threadIdx.x < 32) {
        float s = 0.f;
        #pragma unroll
        for (int m = 0; m < 16; ++m) s += agg[threadIdx.x + 32 * m];
        unsafeAtomicAdd(&pooled[threadIdx.x], s);
    }
}

// ---------------------------------------------------------------------------
// Dual GEMM layer a: h = x@K1 (A), p = x@K2 + b (B).  x:[n,128]
// ---------------------------------------------------------------------------
__device__ __forceinline__ void gemm_row_f128(const float* xr,
                                              const float* __restrict__ K,
                                              float* acc) {
    for (int k = 0; k < 128; ++k) {
        float xv = xr[k];
        const float* Kr = K + k * 32;
        #pragma unroll
        for (int c = 0; c < 32; ++c) acc[c] = fmaf(xv, Kr[c], acc[c]);
    }
}

__global__ __launch_bounds__(128) void gemm_dual_a(
    const float* __restrict__ x, const float* __restrict__ K1,
    const float* __restrict__ K2, const float* __restrict__ bias,
    float* __restrict__ h, float* __restrict__ p, int n)
{
    __shared__ float xs[64 * 129];
    const int base = blockIdx.x * 64;

    for (int i = threadIdx.x; i < 64 * 32; i += 128) {
        int r = i >> 5, c4 = i & 31;
        int node = base + r;
        float4 v = make_float4(0.f, 0.f, 0.f, 0.f);
        if (node < n) v = *(const float4*)(x + (size_t)node * 128 + c4 * 4);
        float* d = &xs[r * 129 + c4 * 4];
        d[0] = v.x; d[1] = v.y; d[2] = v.z; d[3] = v.w;
    }
    __syncthreads();

    const int nl = threadIdx.x & 63;
    const int node = base + nl;
    if (node >= n) return;

    float acc[32];
    #pragma unroll
    for (int c = 0; c < 32; ++c) acc[c] = 0.f;

    const float* xr = &xs[nl * 129];
    if (threadIdx.x < 64) {
        gemm_row_f128(xr, K1, acc);
        float* out = h + (size_t)node * 32;
        #pragma unroll
        for (int c4 = 0; c4 < 8; ++c4)
            *(float4*)(out + c4 * 4) = make_float4(acc[c4*4], acc[c4*4+1], acc[c4*4+2], acc[c4*4+3]);
    } else {
        gemm_row_f128(xr, K2, acc);
        #pragma unroll
        for (int c = 0; c < 32; ++c) acc[c] += bias[c];
        float* out = p + (size_t)node * 32;
        #pragma unroll
        for (int c4 = 0; c4 < 8; ++c4)
            *(float4*)(out + c4 * 4) = make_float4(acc[c4*4], acc[c4*4+1], acc[c4*4+2], acc[c4*4+3]);
    }
}

// ---------------------------------------------------------------------------
// Dual GEMM layer b: reads x1:[n,32] (already relu'd).
// ---------------------------------------------------------------------------
__device__ __forceinline__ void gemm_row_f32(const float* xr,
                                             const float* __restrict__ K,
                                             float* acc) {
    for (int k = 0; k < 32; ++k) {
        float xv = xr[k];
        const float* Kr = K + k * 32;
        #pragma unroll
        for (int c = 0; c < 32; ++c) acc[c] = fmaf(xv, Kr[c], acc[c]);
    }
}

__global__ __launch_bounds__(128) void gemm_dual_b(
    const float* __restrict__ x1,
    const float* __restrict__ K1, const float* __restrict__ K2,
    const float* __restrict__ bias,
    float* __restrict__ h, float* __restrict__ p, int n)
{
    __shared__ float xs[64 * 33];
    const int base = blockIdx.x * 64;

    for (int i = threadIdx.x; i < 64 * 8; i += 128) {
        int r = i >> 3, c4 = i & 7;
        int node = base + r;
        float4 a = make_float4(0.f, 0.f, 0.f, 0.f);
        if (node < n) a = *(const float4*)(x1 + (size_t)node * 32 + c4 * 4);
        float* d = &xs[r * 33 + c4 * 4];
        d[0] = a.x; d[1] = a.y; d[2] = a.z; d[3] = a.w;
    }
    __syncthreads();

    const int nl = threadIdx.x & 63;
    const int node = base + nl;
    if (node >= n) return;

    float acc[32];
    #pragma unroll
    for (int c = 0; c < 32; ++c) acc[c] = 0.f;

    const float* xr = &xs[nl * 33];
    if (threadIdx.x < 64) {
        gemm_row_f32(xr, K1, acc);
        float* out = h + (size_t)node * 32;
        #pragma unroll
        for (int c4 = 0; c4 < 8; ++c4)
            *(float4*)(out + c4 * 4) = make_float4(acc[c4*4], acc[c4*4+1], acc[c4*4+2], acc[c4*4+3]);
    } else {
        gemm_row_f32(xr, K2, acc);
        #pragma unroll
        for (int c = 0; c < 32; ++c) acc[c] += bias[c];
        float* out = p + (size_t)node * 32;
        #pragma unroll
        for (int c4 = 0; c4 < 8; ++c4)
            *(float4*)(out + c4 * 4) = make_float4(acc[c4*4], acc[c4*4+1], acc[c4*4+2], acc[c4*4+3]);
    }
}

// ---------------------------------------------------------------------------
// Fallback (ws too small / nb too large): atomic scatter path.
// ---------------------------------------------------------------------------
__global__ __launch_bounds__(256) void edge_scatter(
    const int* __restrict__ src, const int* __restrict__ dst,
    const float* __restrict__ w, const float* __restrict__ h,
    float* __restrict__ agg, int e)
{
    int t = blockIdx.x * 256 + threadIdx.x;
    int eid = t >> 3, q = t & 7;
    if (eid >= e) return;
    int s = src[eid];
    int d = dst[eid];
    float wv = w[eid];
    float4 hv = *(const float4*)(h + (size_t)s * 32 + q * 4);
    float* ap = agg + (size_t)d * 32 + q * 4;
    unsafeAtomicAdd(ap + 0, hv.x * wv);
    unsafeAtomicAdd(ap + 1, hv.y * wv);
    unsafeAtomicAdd(ap + 2, hv.z * wv);
    unsafeAtomicAdd(ap + 3, hv.w * wv);
}

__global__ __launch_bounds__(256) void relu_add_kernel(
    const float* __restrict__ a, const float* __restrict__ b,
    float* __restrict__ o, size_t m)
{
    size_t i = (size_t)blockIdx.x * 256 + threadIdx.x;
    if (i < m) o[i] = fmaxf(a[i] + b[i], 0.f);
}

__global__ __launch_bounds__(256) void pool_kernel(
    const float* __restrict__ p, const float* __restrict__ agg,
    float* __restrict__ pooled, int n)
{
    const int ch = threadIdx.x & 31;
    const int r  = threadIdx.x >> 5;
    float acc = 0.f;
    for (int node = blockIdx.x * 8 + r; node < n; node += gridDim.x * 8) {
        size_t idx = (size_t)node * 32 + ch;
        acc += fmaxf(p[idx] + agg[idx], 0.f);
    }
    __shared__ float red[256];
    red[threadIdx.x] = acc;
    __syncthreads();
    if (threadIdx.x < 32) {
        float s = 0.f;
        #pragma unroll
        for (int i = 0; i < 8; ++i) s += red[i * 32 + ch];
        unsafeAtomicAdd(&pooled[ch], s);
    }
}

__global__ void dense_kernel(
    const float* __restrict__ pooled,
    const float* __restrict__ Wd1, const float* __restrict__ bd1,
    const float* __restrict__ Wd2, const float* __restrict__ bd2,
    float* __restrict__ out)
{
    int j = threadIdx.x;
    float t = 0.f;
    if (j < 24) {
        t = bd1[j];
        #pragma unroll
        for (int c = 0; c < 32; ++c) t = fmaf(pooled[c], Wd1[c * 24 + j], t);
        t *= Wd2[j];
    }
    #pragma unroll
    for (int off = 32; off > 0; off >>= 1) t += __shfl_down(t, off, 64);
    if (j == 0) out[0] = t + bd2[0];
}

extern "C" void kernel_launch(void* const* d_in, const int* in_sizes, int n_in,
                              void* d_out, int out_size, void* d_ws, size_t ws_size,
                              hipStream_t stream) {
    const float* x   = (const float*)d_in[0];
    const int*   esrc= (const int*)d_in[1];
    const int*   edst= (const int*)d_in[2];
    const float* ew  = (const float*)d_in[3];
    const float* K1a = (const float*)d_in[4];
    const float* K2a = (const float*)d_in[5];
    const float* ba  = (const float*)d_in[6];
    const float* K1b = (const float*)d_in[7];
    const float* K2b = (const float*)d_in[8];
    const float* bb  = (const float*)d_in[9];
    const float* Wd1 = (const float*)d_in[10];
    const float* bd1 = (const float*)d_in[11];
    const float* Wd2 = (const float*)d_in[12];
    const float* bd2 = (const float*)d_in[13];

    const int n = in_sizes[0] / 128;   // 100000
    const int e = in_sizes[1];         // 3200000
    const size_t nc = (size_t)n * 32;
    const int nb = (n + NPB - 1) / NPB;            // 391
    const int nruns = (e + CHUNK - 1) / CHUNK;     // 391

    // ws layout: etmp[e] ull | A[nc] | B[nc] | Cg[nc] | pooled[32] | runoff
    const size_t need = (size_t)e * 8 + 3 * nc * 4 + 32 * 4
                      + (size_t)nruns * (nb + 1) * 4;

    const int gemm_blocks = (n + 63) / 64;

    if (ws_size >= need && nb <= NBMAX) {
        char* wp = (char*)d_ws;
        ull* etmp = (ull*)wp;                 wp += (size_t)e * 8;
        float* A = (float*)wp;                wp += nc * 4;   // h
        float* B = (float*)wp;                wp += nc * 4;   // p
        float* Cg = (float*)wp;               wp += nc * 4;   // x1
        float* pooled = (float*)wp;           wp += 32 * 4;
        int* runoff = (int*)wp;

        hipMemsetAsync(pooled, 0, 32 * 4, stream);

        build_runs_kernel<<<nruns, 512, 0, stream>>>(esrc, edst, ew, etmp, runoff,
                                                     e, nruns, nb);
        gemm_dual_a<<<gemm_blocks, 128, 0, stream>>>(x, K1a, K2a, ba, A, B, n);
        fused_gather_x1<<<nb, 512, 0, stream>>>(etmp, runoff, A, B, Cg, n, nruns, nb);
        gemm_dual_b<<<gemm_blocks, 128, 0, stream>>>(Cg, K1b, K2b, bb, A, B, n);
        fused_gather_pool<<<nb, 512, 0, stream>>>(etmp, runoff, A, B, pooled, n, nruns, nb);
        dense_kernel<<<1, 64, 0, stream>>>(pooled, Wd1, bd1, Wd2, bd2, (float*)d_out);
    } else {
        // fallback: atomic scatter path
        float* A      = (float*)d_ws;
        float* B      = A + nc;
        float* Cg     = B + nc;
        float* pooled = Cg + nc;
        const int edge_blocks_8 = (int)(((long long)e * 8 + 255) / 256);

        hipMemsetAsync(Cg, 0, nc * 4, stream);
        gemm_dual_a<<<gemm_blocks, 128, 0, stream>>>(x, K1a, K2a, ba, A, B, n);
        edge_scatter<<<edge_blocks_8, 256, 0, stream>>>(esrc, edst, ew, A, Cg, e);
        relu_add_kernel<<<(int)((nc + 255) / 256), 256, 0, stream>>>(B, Cg, B, nc);
        gemm_dual_b<<<gemm_blocks, 128, 0, stream>>>(B, K1b, K2b, bb, A, Cg, n);
        hipMemsetAsync(B, 0, nc * 4, stream);
        edge_scatter<<<edge_blocks_8, 256, 0, stream>>>(esrc, edst, ew, A, B, e);
        hipMemsetAsync(pooled, 0, 32 * 4, stream);
        pool_kernel<<<1024, 256, 0, stream>>>(Cg, B, pooled, n);
        dense_kernel<<<1, 64, 0, stream>>>(pooled, Wd1, bd1, Wd2, bd2, (float*)d_out);
    }
}

// Round 5
// 292.179 us; speedup vs baseline: 5.2404x; 5.2404x over previous
//
#include <hip/hip_runtime.h>

typedef unsigned long long ull;

// Problem constants: N=100000 nodes, E=3200000 edges, F=128, C=32, H=24
//
// Pipeline:
//   1. build_runs:   8192 edges/block counting-sorted by coarse bucket
//                    (dst>>8) fully inside LDS; coalesced write of the
//                    bucket-grouped run + runoff[r][b] segment table;
//                    per-bucket totals accumulated.
//   2. bucket_scan:  exclusive scan of bucket totals -> bucket_base.
//   3. sort_buckets: one block per bucket; count dloc hist from the bucket's
//                    segments, scan -> row[], scatter records into LDS stage,
//                    coalesced copy-out to dst-sorted epack.
//   4. gemm_dual_a:  h_a = x@K1a, p_a = x@K2a + ba
//   5. gather_x1:    x1 = relu(csr_gather(h_a) + p_a)       (8 thr/node)
//   6. gemm_dual_b:  h_b = x1@K1b, p_b = x1@K2b + bb
//   7. gather_pool:  pooled += relu(csr_gather(h_b) + p_b)  (32 atomics/blk)
//   8. dense epilogue
//
// record: low = src | (dst&255)<<20 ; high = f32 bits of w   (src < 2^20)

#define CHUNK    8192
#define NPB      256
#define NBMAX    512
#define STAGECAP 9216   // 72 KB; max bucket ~ 8192 + 4 sigma (~90/sigma)

// ---------------------------------------------------------------------------
// Phase 1: LDS-staged counting sort of each 8192-edge chunk by bucket.
// ---------------------------------------------------------------------------
__global__ __launch_bounds__(512) void build_runs_kernel(
    const int* __restrict__ src, const int* __restrict__ dst,
    const float* __restrict__ w,
    ull* __restrict__ etmp, int* __restrict__ runoff,
    int* __restrict__ bucket_cnt, int e, int nruns, int nb)
{
    __shared__ ull stage[CHUNK];      // 64 KB
    __shared__ int hist[NBMAX];
    __shared__ int scn[NBMAX];
    const int r = blockIdx.x, tid = threadIdx.x;
    const int base = r * CHUNK;
    const int cnt = min(CHUNK, e - base);

    hist[tid] = 0;
    __syncthreads();

    int dreg[CHUNK / 512];
    #pragma unroll
    for (int k = 0; k < CHUNK / 512; ++k) {
        int i = tid + k * 512;
        int d = (i < cnt) ? dst[base + i] : -1;
        dreg[k] = d;
        if (d >= 0) atomicAdd(&hist[d >> 8], 1);
    }
    __syncthreads();

    // exclusive scan over NBMAX entries
    int v = hist[tid];
    scn[tid] = v;
    __syncthreads();
    for (int off = 1; off < NBMAX; off <<= 1) {
        int u = (tid >= off) ? scn[tid - off] : 0;
        __syncthreads();
        scn[tid] += u;
        __syncthreads();
    }
    const int ex = scn[tid] - v;
    if (tid < nb && v) atomicAdd(&bucket_cnt[tid], v);
    hist[tid] = ex;                   // becomes cursor
    if (tid <= nb) runoff[(size_t)r * (nb + 1) + tid] = base + ex;
    __syncthreads();

    // scatter into LDS stage
    #pragma unroll
    for (int k = 0; k < CHUNK / 512; ++k) {
        int i = tid + k * 512;
        int d = dreg[k];
        if (d >= 0) {
            int pos = atomicAdd(&hist[d >> 8], 1);
            unsigned lo = (unsigned)src[base + i] | ((unsigned)(d & 255) << 20);
            stage[pos] = (ull)lo | ((ull)__float_as_uint(w[base + i]) << 32);
        }
    }
    __syncthreads();

    // coalesced copy-out
    for (int i = tid; i < cnt; i += 512) etmp[base + i] = stage[i];
}

__global__ __launch_bounds__(512) void bucket_scan_kernel(
    const int* __restrict__ cnt, int* __restrict__ basep, int nb, int e)
{
    __shared__ int s[512];
    int t = threadIdx.x;
    int v = (t < nb) ? cnt[t] : 0;
    s[t] = v; __syncthreads();
    for (int off = 1; off < 512; off <<= 1) {
        int u = (t >= off) ? s[t - off] : 0;
        __syncthreads(); s[t] += u; __syncthreads();
    }
    if (t < nb) basep[t] = s[t] - v;
    if (t == 0) basep[nb] = e;
}

// ---------------------------------------------------------------------------
// Phase 3: fine sort per bucket. Count -> scan (row[]) -> LDS-stage scatter
// -> coalesced copy-out. 64 streams of 8 lanes walk the bucket's segments.
// ---------------------------------------------------------------------------
__global__ __launch_bounds__(512) void sort_buckets_kernel(
    const ull* __restrict__ etmp, const int* __restrict__ runoff,
    const int* __restrict__ bbase,
    ull* __restrict__ epack, int* __restrict__ row,
    int n, int e, int nruns, int nb)
{
    __shared__ ull stage[STAGECAP];   // 72 KB
    __shared__ int hist[NPB];
    __shared__ int scn[NPB];
    __shared__ int cur[NPB];
    const int b = blockIdx.x, tid = threadIdx.x;
    const int base0 = bbase[b];
    const int cnt = bbase[b + 1] - base0;

    if (tid < NPB) hist[tid] = 0;
    __syncthreads();

    const int stream = tid >> 3, sub = tid & 7;   // 64 streams x 8 lanes
    const int* rs = runoff;

    for (int r = stream; r < nruns; r += 64) {
        int s0 = rs[(size_t)r * (nb + 1) + b];
        int s1 = rs[(size_t)r * (nb + 1) + b + 1];
        for (int i = s0 + sub; i < s1; i += 8)
            atomicAdd(&hist[(int)((etmp[i] >> 20) & 255u)], 1);
    }
    __syncthreads();

    // exclusive scan over NPB=256 entries (threads 0..255 active)
    int v = (tid < NPB) ? hist[tid] : 0;
    if (tid < NPB) scn[tid] = v;
    __syncthreads();
    for (int off = 1; off < NPB; off <<= 1) {
        int u = (tid >= off && tid < NPB) ? scn[tid - off] : 0;
        __syncthreads();
        if (tid < NPB) scn[tid] += u;
        __syncthreads();
    }
    if (tid < NPB) {
        int ex = scn[tid] - v;
        cur[tid] = ex;
        int node = b * NPB + tid;
        if (node < n) row[node] = base0 + ex;
    }
    if (b == nb - 1 && tid == 0) row[n] = e;
    __syncthreads();

    if (cnt <= STAGECAP) {
        for (int r = stream; r < nruns; r += 64) {
            int s0 = rs[(size_t)r * (nb + 1) + b];
            int s1 = rs[(size_t)r * (nb + 1) + b + 1];
            for (int i = s0 + sub; i < s1; i += 8) {
                ull pk = etmp[i];
                int pos = atomicAdd(&cur[(int)((pk >> 20) & 255u)], 1);
                stage[pos] = pk;
            }
        }
        __syncthreads();
        for (int i = tid; i < cnt; i += 512) epack[(size_t)base0 + i] = stage[i];
    } else {
        // overflow safety: direct global scatter (own window, single CU)
        for (int r = stream; r < nruns; r += 64) {
            int s0 = rs[(size_t)r * (nb + 1) + b];
            int s1 = rs[(size_t)r * (nb + 1) + b + 1];
            for (int i = s0 + sub; i < s1; i += 8) {
                ull pk = etmp[i];
                int pos = atomicAdd(&cur[(int)((pk >> 20) & 255u)], 1);
                epack[(size_t)base0 + pos] = pk;
            }
        }
    }
}

// ---------------------------------------------------------------------------
// Dual GEMM layer a: h = x@K1 (A), p = x@K2 + b (B).  x:[n,128]
// ---------------------------------------------------------------------------
__device__ __forceinline__ void gemm_row_f128(const float* xr,
                                              const float* __restrict__ K,
                                              float* acc) {
    for (int k = 0; k < 128; ++k) {
        float xv = xr[k];
        const float* Kr = K + k * 32;
        #pragma unroll
        for (int c = 0; c < 32; ++c) acc[c] = fmaf(xv, Kr[c], acc[c]);
    }
}

__global__ __launch_bounds__(128) void gemm_dual_a(
    const float* __restrict__ x, const float* __restrict__ K1,
    const float* __restrict__ K2, const float* __restrict__ bias,
    float* __restrict__ h, float* __restrict__ p, int n)
{
    __shared__ float xs[64 * 129];
    const int base = blockIdx.x * 64;

    for (int i = threadIdx.x; i < 64 * 32; i += 128) {
        int r = i >> 5, c4 = i & 31;
        int node = base + r;
        float4 v = make_float4(0.f, 0.f, 0.f, 0.f);
        if (node < n) v = *(const float4*)(x + (size_t)node * 128 + c4 * 4);
        float* d = &xs[r * 129 + c4 * 4];
        d[0] = v.x; d[1] = v.y; d[2] = v.z; d[3] = v.w;
    }
    __syncthreads();

    const int nl = threadIdx.x & 63;
    const int node = base + nl;
    if (node >= n) return;

    float acc[32];
    #pragma unroll
    for (int c = 0; c < 32; ++c) acc[c] = 0.f;

    const float* xr = &xs[nl * 129];
    if (threadIdx.x < 64) {
        gemm_row_f128(xr, K1, acc);
        float* out = h + (size_t)node * 32;
        #pragma unroll
        for (int c4 = 0; c4 < 8; ++c4)
            *(float4*)(out + c4 * 4) = make_float4(acc[c4*4], acc[c4*4+1], acc[c4*4+2], acc[c4*4+3]);
    } else {
        gemm_row_f128(xr, K2, acc);
        #pragma unroll
        for (int c = 0; c < 32; ++c) acc[c] += bias[c];
        float* out = p + (size_t)node * 32;
        #pragma unroll
        for (int c4 = 0; c4 < 8; ++c4)
            *(float4*)(out + c4 * 4) = make_float4(acc[c4*4], acc[c4*4+1], acc[c4*4+2], acc[c4*4+3]);
    }
}

// ---------------------------------------------------------------------------
// Dual GEMM layer b: reads x1:[n,32] (already relu'd).
// ---------------------------------------------------------------------------
__device__ __forceinline__ void gemm_row_f32(const float* xr,
                                             const float* __restrict__ K,
                                             float* acc) {
    for (int k = 0; k < 32; ++k) {
        float xv = xr[k];
        const float* Kr = K + k * 32;
        #pragma unroll
        for (int c = 0; c < 32; ++c) acc[c] = fmaf(xv, Kr[c], acc[c]);
    }
}

__global__ __launch_bounds__(128) void gemm_dual_b(
    const float* __restrict__ x1,
    const float* __restrict__ K1, const float* __restrict__ K2,
    const float* __restrict__ bias,
    float* __restrict__ h, float* __restrict__ p, int n)
{
    __shared__ float xs[64 * 33];
    const int base = blockIdx.x * 64;

    for (int i = threadIdx.x; i < 64 * 8; i += 128) {
        int r = i >> 3, c4 = i & 7;
        int node = base + r;
        float4 a = make_float4(0.f, 0.f, 0.f, 0.f);
        if (node < n) a = *(const float4*)(x1 + (size_t)node * 32 + c4 * 4);
        float* d = &xs[r * 33 + c4 * 4];
        d[0] = a.x; d[1] = a.y; d[2] = a.z; d[3] = a.w;
    }
    __syncthreads();

    const int nl = threadIdx.x & 63;
    const int node = base + nl;
    if (node >= n) return;

    float acc[32];
    #pragma unroll
    for (int c = 0; c < 32; ++c) acc[c] = 0.f;

    const float* xr = &xs[nl * 33];
    if (threadIdx.x < 64) {
        gemm_row_f32(xr, K1, acc);
        float* out = h + (size_t)node * 32;
        #pragma unroll
        for (int c4 = 0; c4 < 8; ++c4)
            *(float4*)(out + c4 * 4) = make_float4(acc[c4*4], acc[c4*4+1], acc[c4*4+2], acc[c4*4+3]);
    } else {
        gemm_row_f32(xr, K2, acc);
        #pragma unroll
        for (int c = 0; c < 32; ++c) acc[c] += bias[c];
        float* out = p + (size_t)node * 32;
        #pragma unroll
        for (int c4 = 0; c4 < 8; ++c4)
            *(float4*)(out + c4 * 4) = make_float4(acc[c4*4], acc[c4*4+1], acc[c4*4+2], acc[c4*4+3]);
    }
}

// ---------------------------------------------------------------------------
// CSR gather core: 8 threads/node, 2-way unrolled for load ILP.
// ---------------------------------------------------------------------------
__device__ __forceinline__ float4 gather_node(
    const int* __restrict__ row, const ull* __restrict__ epack,
    const float* __restrict__ h, int node, int q)
{
    int r0 = row[node], r1 = row[node + 1];
    float4 a = make_float4(0.f, 0.f, 0.f, 0.f);
    float4 b = make_float4(0.f, 0.f, 0.f, 0.f);
    int i = r0;
    for (; i + 1 < r1; i += 2) {
        ull p0 = epack[i], p1 = epack[i + 1];
        int s0 = (int)(p0 & 0xFFFFFu);
        int s1 = (int)(p1 & 0xFFFFFu);
        float w0 = __uint_as_float((unsigned)(p0 >> 32));
        float w1 = __uint_as_float((unsigned)(p1 >> 32));
        float4 h0 = *(const float4*)(h + (size_t)s0 * 32 + q * 4);
        float4 h1 = *(const float4*)(h + (size_t)s1 * 32 + q * 4);
        a.x = fmaf(w0, h0.x, a.x); a.y = fmaf(w0, h0.y, a.y);
        a.z = fmaf(w0, h0.z, a.z); a.w = fmaf(w0, h0.w, a.w);
        b.x = fmaf(w1, h1.x, b.x); b.y = fmaf(w1, h1.y, b.y);
        b.z = fmaf(w1, h1.z, b.z); b.w = fmaf(w1, h1.w, b.w);
    }
    if (i < r1) {
        ull p0 = epack[i];
        int s0 = (int)(p0 & 0xFFFFFu);
        float w0 = __uint_as_float((unsigned)(p0 >> 32));
        float4 h0 = *(const float4*)(h + (size_t)s0 * 32 + q * 4);
        a.x = fmaf(w0, h0.x, a.x); a.y = fmaf(w0, h0.y, a.y);
        a.z = fmaf(w0, h0.z, a.z); a.w = fmaf(w0, h0.w, a.w);
    }
    a.x += b.x; a.y += b.y; a.z += b.z; a.w += b.w;
    return a;
}

__global__ __launch_bounds__(256) void gather_x1_kernel(
    const int* __restrict__ row, const ull* __restrict__ epack,
    const float* __restrict__ h, const float* __restrict__ p,
    float* __restrict__ x1, int n)
{
    const int q = threadIdx.x & 7;
    const int node = blockIdx.x * 32 + (threadIdx.x >> 3);
    if (node >= n) return;
    float4 acc = gather_node(row, epack, h, node, q);
    const float4 pv = *(const float4*)(p + (size_t)node * 32 + q * 4);
    float4 o;
    o.x = fmaxf(acc.x + pv.x, 0.f);
    o.y = fmaxf(acc.y + pv.y, 0.f);
    o.z = fmaxf(acc.z + pv.z, 0.f);
    o.w = fmaxf(acc.w + pv.w, 0.f);
    *(float4*)(x1 + (size_t)node * 32 + q * 4) = o;
}

__global__ __launch_bounds__(256) void gather_pool_kernel(
    const int* __restrict__ row, const ull* __restrict__ epack,
    const float* __restrict__ h, const float* __restrict__ p,
    float* __restrict__ pooled, int n)
{
    const int q = threadIdx.x & 7;
    const int node = blockIdx.x * 32 + (threadIdx.x >> 3);

    float4 o = make_float4(0.f, 0.f, 0.f, 0.f);
    if (node < n) {
        float4 acc = gather_node(row, epack, h, node, q);
        const float4 pv = *(const float4*)(p + (size_t)node * 32 + q * 4);
        o.x = fmaxf(acc.x + pv.x, 0.f);
        o.y = fmaxf(acc.y + pv.y, 0.f);
        o.z = fmaxf(acc.z + pv.z, 0.f);
        o.w = fmaxf(acc.w + pv.w, 0.f);
    }
    __shared__ float red[256][4];
    red[threadIdx.x][0] = o.x; red[threadIdx.x][1] = o.y;
    red[threadIdx.x][2] = o.z; red[threadIdx.x][3] = o.w;
    __syncthreads();
    if (threadIdx.x < 32) {
        const int c = threadIdx.x;
        const int cq = c >> 2, cj = c & 3;
        float s = 0.f;
        #pragma unroll
        for (int l = 0; l < 32; ++l) s += red[l * 8 + cq][cj];
        unsafeAtomicAdd(&pooled[c], s);
    }
}

// ---------------------------------------------------------------------------
// Fallback (ws too small / nb too large): atomic scatter path.
// ---------------------------------------------------------------------------
__global__ __launch_bounds__(256) void edge_scatter(
    const int* __restrict__ src, const int* __restrict__ dst,
    const float* __restrict__ w, const float* __restrict__ h,
    float* __restrict__ agg, int e)
{
    int t = blockIdx.x * 256 + threadIdx.x;
    int eid = t >> 3, q = t & 7;
    if (eid >= e) return;
    int s = src[eid];
    int d = dst[eid];
    float wv = w[eid];
    float4 hv = *(const float4*)(h + (size_t)s * 32 + q * 4);
    float* ap = agg + (size_t)d * 32 + q * 4;
    unsafeAtomicAdd(ap + 0, hv.x * wv);
    unsafeAtomicAdd(ap + 1, hv.y * wv);
    unsafeAtomicAdd(ap + 2, hv.z * wv);
    unsafeAtomicAdd(ap + 3, hv.w * wv);
}

__global__ __launch_bounds__(256) void relu_add_kernel(
    const float* __restrict__ a, const float* __restrict__ b,
    float* __restrict__ o, size_t m)
{
    size_t i = (size_t)blockIdx.x * 256 + threadIdx.x;
    if (i < m) o[i] = fmaxf(a[i] + b[i], 0.f);
}

__global__ __launch_bounds__(256) void pool_kernel(
    const float* __restrict__ p, const float* __restrict__ agg,
    float* __restrict__ pooled, int n)
{
    const int ch = threadIdx.x & 31;
    const int r  = threadIdx.x >> 5;
    float acc = 0.f;
    for (int node = blockIdx.x * 8 + r; node < n; node += gridDim.x * 8) {
        size_t idx = (size_t)node * 32 + ch;
        acc += fmaxf(p[idx] + agg[idx], 0.f);
    }
    __shared__ float red[256];
    red[threadIdx.x] = acc;
    __syncthreads();
    if (threadIdx.x < 32) {
        float s = 0.f;
        #pragma unroll
        for (int i = 0; i < 8; ++i) s += red[i * 32 + ch];
        unsafeAtomicAdd(&pooled[ch], s);
    }
}

__global__ void dense_kernel(
    const float* __restrict__ pooled,
    const float* __restrict__ Wd1, const float* __restrict__ bd1,
    const float* __restrict__ Wd2, const float* __restrict__ bd2,
    float* __restrict__ out)
{
    int j = threadIdx.x;
    float t = 0.f;
    if (j < 24) {
        t = bd1[j];
        #pragma unroll
        for (int c = 0; c < 32; ++c) t = fmaf(pooled[c], Wd1[c * 24 + j], t);
        t *= Wd2[j];
    }
    #pragma unroll
    for (int off = 32; off > 0; off >>= 1) t += __shfl_down(t, off, 64);
    if (j == 0) out[0] = t + bd2[0];
}

extern "C" void kernel_launch(void* const* d_in, const int* in_sizes, int n_in,
                              void* d_out, int out_size, void* d_ws, size_t ws_size,
                              hipStream_t stream) {
    const float* x   = (const float*)d_in[0];
    const int*   esrc= (const int*)d_in[1];
    const int*   edst= (const int*)d_in[2];
    const float* ew  = (const float*)d_in[3];
    const float* K1a = (const float*)d_in[4];
    const float* K2a = (const float*)d_in[5];
    const float* ba  = (const float*)d_in[6];
    const float* K1b = (const float*)d_in[7];
    const float* K2b = (const float*)d_in[8];
    const float* bb  = (const float*)d_in[9];
    const float* Wd1 = (const float*)d_in[10];
    const float* bd1 = (const float*)d_in[11];
    const float* Wd2 = (const float*)d_in[12];
    const float* bd2 = (const float*)d_in[13];

    const int n = in_sizes[0] / 128;   // 100000
    const int e = in_sizes[1];         // 3200000
    const size_t nc = (size_t)n * 32;
    const int nb = (n + NPB - 1) / NPB;            // 391
    const int nruns = (e + CHUNK - 1) / CHUNK;     // 391

    // ws layout:
    //   epack [e] ull                 (persists through gathers)
    //   etmp  [e] ull  -> reused as A[nc], B[nc] after sort_buckets
    //   Cg    [nc] f32
    //   pooled [32] f32
    //   row   [n+1] int
    //   bucket_cnt [nb] int | bucket_base [nb+1] int
    //   runoff [nruns*(nb+1)] int
    const size_t etmp_bytes = ((size_t)e * 8 > 2 * nc * 4) ? (size_t)e * 8 : 2 * nc * 4;
    const size_t need = (size_t)e * 8 + etmp_bytes + nc * 4 + 32 * 4
                      + (size_t)(n + 1) * 4 + (size_t)nb * 4 + (size_t)(nb + 1) * 4
                      + (size_t)nruns * (nb + 1) * 4;

    const int gemm_blocks   = (n + 63) / 64;
    const int gather_blocks = (n + 31) / 32;

    if (ws_size >= need && nb <= NBMAX) {
        char* wp = (char*)d_ws;
        ull* epack = (ull*)wp;                wp += (size_t)e * 8;
        ull* etmp  = (ull*)wp;
        float* A = (float*)etmp;              // aliases etmp after sort
        float* B = A + nc;                    wp += etmp_bytes;
        float* Cg = (float*)wp;               wp += nc * 4;
        float* pooled = (float*)wp;           wp += 32 * 4;
        int* row = (int*)wp;                  wp += (size_t)(n + 1) * 4;
        int* bucket_cnt = (int*)wp;           wp += (size_t)nb * 4;
        int* bucket_base = (int*)wp;          wp += (size_t)(nb + 1) * 4;
        int* runoff = (int*)wp;

        hipMemsetAsync(bucket_cnt, 0, (size_t)nb * 4, stream);
        hipMemsetAsync(pooled, 0, 32 * 4, stream);

        build_runs_kernel<<<nruns, 512, 0, stream>>>(esrc, edst, ew, etmp, runoff,
                                                     bucket_cnt, e, nruns, nb);
        bucket_scan_kernel<<<1, 512, 0, stream>>>(bucket_cnt, bucket_base, nb, e);
        sort_buckets_kernel<<<nb, 512, 0, stream>>>(etmp, runoff, bucket_base,
                                                    epack, row, n, e, nruns, nb);
        // etmp is dead now; its storage becomes A,B.
        gemm_dual_a<<<gemm_blocks, 128, 0, stream>>>(x, K1a, K2a, ba, A, B, n);
        gather_x1_kernel<<<gather_blocks, 256, 0, stream>>>(row, epack, A, B, Cg, n);
        gemm_dual_b<<<gemm_blocks, 128, 0, stream>>>(Cg, K1b, K2b, bb, A, B, n);
        gather_pool_kernel<<<gather_blocks, 256, 0, stream>>>(row, epack, A, B, pooled, n);
        dense_kernel<<<1, 64, 0, stream>>>(pooled, Wd1, bd1, Wd2, bd2, (float*)d_out);
    } else {
        // fallback: atomic scatter path
        float* A      = (float*)d_ws;
        float* B      = A + nc;
        float* Cg     = B + nc;
        float* pooled = Cg + nc;
        const int edge_blocks_8 = (int)(((long long)e * 8 + 255) / 256);

        hipMemsetAsync(Cg, 0, nc * 4, stream);
        gemm_dual_a<<<gemm_blocks, 128, 0, stream>>>(x, K1a, K2a, ba, A, B, n);
        edge_scatter<<<edge_blocks_8, 256, 0, stream>>>(esrc, edst, ew, A, Cg, e);
        relu_add_kernel<<<(int)((nc + 255) / 256), 256, 0, stream>>>(B, Cg, B, nc);
        gemm_dual_b<<<gemm_blocks, 128, 0, stream>>>(B, K1b, K2b, bb, A, Cg, n);
        hipMemsetAsync(B, 0, nc * 4, stream);
        edge_scatter<<<edge_blocks_8, 256, 0, stream>>>(esrc, edst, ew, A, B, e);
        hipMemsetAsync(pooled, 0, 32 * 4, stream);
        pool_kernel<<<1024, 256, 0, stream>>>(Cg, B, pooled, n);
        dense_kernel<<<1, 64, 0, stream>>>(pooled, Wd1, bd1, Wd2, bd2, (float*)d_out);
    }
}

// Round 6
// 272.351 us; speedup vs baseline: 5.6219x; 1.0728x over previous
//
#include <hip/hip_runtime.h>
#include <hip/hip_bf16.h>

typedef unsigned long long ull;
typedef unsigned int uint;

// Problem constants: N=100000 nodes, E=3200000 edges, F=128, C=32, H=24
//
// Pipeline:
//   1. build_runs:   8192 edges/block counting-sorted by coarse bucket
//                    (dst>>8) fully inside LDS; coalesced write + runoff table
//   2. bucket_scan:  exclusive scan of bucket totals -> bucket_base
//   3. sort_buckets: block/bucket fine sort (LDS stage) -> epack, row[]
//   4. gemm_dual_a:  h_a = x@K1a (bf16), p_a = x@K2a + ba (f32)
//   5. gather_x1:    x1 = relu(csr_gather(h_a) + p_a)   [bf16 h: 64 B/edge]
//   6. gemm_dual_b:  h_b = x1@K1b (bf16), p_b = x1@K2b + bb (f32)
//   7. gather_pool:  pooled += relu(csr_gather(h_b) + p_b)
//   8. dense epilogue
//
// record: low = src | (dst&255)<<20 ; high = f32 bits of w   (src < 2^20)

#define CHUNK    8192
#define NPB      256
#define NBMAX    512
#define STAGECAP 9216   // 72 KB

// ---------------------------------------------------------------------------
// Phase 1: LDS-staged counting sort of each 8192-edge chunk by bucket.
// ---------------------------------------------------------------------------
__global__ __launch_bounds__(512) void build_runs_kernel(
    const int* __restrict__ src, const int* __restrict__ dst,
    const float* __restrict__ w,
    ull* __restrict__ etmp, int* __restrict__ runoff,
    int* __restrict__ bucket_cnt, int e, int nruns, int nb)
{
    __shared__ ull stage[CHUNK];      // 64 KB
    __shared__ int hist[NBMAX];
    __shared__ int scn[NBMAX];
    const int r = blockIdx.x, tid = threadIdx.x;
    const int base = r * CHUNK;
    const int cnt = min(CHUNK, e - base);

    hist[tid] = 0;
    __syncthreads();

    int dreg[CHUNK / 512];
    #pragma unroll
    for (int k = 0; k < CHUNK / 512; ++k) {
        int i = tid + k * 512;
        int d = (i < cnt) ? dst[base + i] : -1;
        dreg[k] = d;
        if (d >= 0) atomicAdd(&hist[d >> 8], 1);
    }
    __syncthreads();

    int v = hist[tid];
    scn[tid] = v;
    __syncthreads();
    for (int off = 1; off < NBMAX; off <<= 1) {
        int u = (tid >= off) ? scn[tid - off] : 0;
        __syncthreads();
        scn[tid] += u;
        __syncthreads();
    }
    const int ex = scn[tid] - v;
    if (tid < nb && v) atomicAdd(&bucket_cnt[tid], v);
    hist[tid] = ex;                   // becomes cursor
    if (tid <= nb) runoff[(size_t)r * (nb + 1) + tid] = base + ex;
    __syncthreads();

    #pragma unroll
    for (int k = 0; k < CHUNK / 512; ++k) {
        int i = tid + k * 512;
        int d = dreg[k];
        if (d >= 0) {
            int pos = atomicAdd(&hist[d >> 8], 1);
            unsigned lo = (unsigned)src[base + i] | ((unsigned)(d & 255) << 20);
            stage[pos] = (ull)lo | ((ull)__float_as_uint(w[base + i]) << 32);
        }
    }
    __syncthreads();

    for (int i = tid; i < cnt; i += 512) etmp[base + i] = stage[i];
}

__global__ __launch_bounds__(512) void bucket_scan_kernel(
    const int* __restrict__ cnt, int* __restrict__ basep, int nb, int e)
{
    __shared__ int s[512];
    int t = threadIdx.x;
    int v = (t < nb) ? cnt[t] : 0;
    s[t] = v; __syncthreads();
    for (int off = 1; off < 512; off <<= 1) {
        int u = (t >= off) ? s[t - off] : 0;
        __syncthreads(); s[t] += u; __syncthreads();
    }
    if (t < nb) basep[t] = s[t] - v;
    if (t == 0) basep[nb] = e;
}

// ---------------------------------------------------------------------------
// Phase 3: fine sort per bucket (LDS stage, coalesced copy-out).
// ---------------------------------------------------------------------------
__global__ __launch_bounds__(512) void sort_buckets_kernel(
    const ull* __restrict__ etmp, const int* __restrict__ runoff,
    const int* __restrict__ bbase,
    ull* __restrict__ epack, int* __restrict__ row,
    int n, int e, int nruns, int nb)
{
    __shared__ ull stage[STAGECAP];   // 72 KB
    __shared__ int hist[NPB];
    __shared__ int scn[NPB];
    __shared__ int cur[NPB];
    const int b = blockIdx.x, tid = threadIdx.x;
    const int base0 = bbase[b];
    const int cnt = bbase[b + 1] - base0;

    if (tid < NPB) hist[tid] = 0;
    __syncthreads();

    const int stream = tid >> 3, sub = tid & 7;   // 64 streams x 8 lanes
    const int* rs = runoff;

    for (int r = stream; r < nruns; r += 64) {
        int s0 = rs[(size_t)r * (nb + 1) + b];
        int s1 = rs[(size_t)r * (nb + 1) + b + 1];
        for (int i = s0 + sub; i < s1; i += 8)
            atomicAdd(&hist[(int)((etmp[i] >> 20) & 255u)], 1);
    }
    __syncthreads();

    int v = (tid < NPB) ? hist[tid] : 0;
    if (tid < NPB) scn[tid] = v;
    __syncthreads();
    for (int off = 1; off < NPB; off <<= 1) {
        int u = (tid >= off && tid < NPB) ? scn[tid - off] : 0;
        __syncthreads();
        if (tid < NPB) scn[tid] += u;
        __syncthreads();
    }
    if (tid < NPB) {
        int ex = scn[tid] - v;
        cur[tid] = ex;
        int node = b * NPB + tid;
        if (node < n) row[node] = base0 + ex;
    }
    if (b == nb - 1 && tid == 0) row[n] = e;
    __syncthreads();

    if (cnt <= STAGECAP) {
        for (int r = stream; r < nruns; r += 64) {
            int s0 = rs[(size_t)r * (nb + 1) + b];
            int s1 = rs[(size_t)r * (nb + 1) + b + 1];
            for (int i = s0 + sub; i < s1; i += 8) {
                ull pk = etmp[i];
                int pos = atomicAdd(&cur[(int)((pk >> 20) & 255u)], 1);
                stage[pos] = pk;
            }
        }
        __syncthreads();
        for (int i = tid; i < cnt; i += 512) epack[(size_t)base0 + i] = stage[i];
    } else {
        for (int r = stream; r < nruns; r += 64) {
            int s0 = rs[(size_t)r * (nb + 1) + b];
            int s1 = rs[(size_t)r * (nb + 1) + b + 1];
            for (int i = s0 + sub; i < s1; i += 8) {
                ull pk = etmp[i];
                int pos = atomicAdd(&cur[(int)((pk >> 20) & 255u)], 1);
                epack[(size_t)base0 + pos] = pk;
            }
        }
    }
}

// ---------------------------------------------------------------------------
// bf16 helpers
// ---------------------------------------------------------------------------
__device__ __forceinline__ void store_row_bf16(ushort* out, const float* acc) {
    uint u[16];
    #pragma unroll
    for (int k = 0; k < 16; ++k) {
        __hip_bfloat16 b0 = __float2bfloat16(acc[2 * k]);
        __hip_bfloat16 b1 = __float2bfloat16(acc[2 * k + 1]);
        u[k] = (uint)(*reinterpret_cast<ushort*>(&b0)) |
               ((uint)(*reinterpret_cast<ushort*>(&b1)) << 16);
    }
    uint4* o = (uint4*)out;
    o[0] = make_uint4(u[0], u[1], u[2], u[3]);
    o[1] = make_uint4(u[4], u[5], u[6], u[7]);
    o[2] = make_uint4(u[8], u[9], u[10], u[11]);
    o[3] = make_uint4(u[12], u[13], u[14], u[15]);
}

__device__ __forceinline__ void bf16x4_decode(uint2 hv, float& f0, float& f1,
                                              float& f2, float& f3) {
    f0 = __uint_as_float(hv.x << 16);
    f1 = __uint_as_float(hv.x & 0xFFFF0000u);
    f2 = __uint_as_float(hv.y << 16);
    f3 = __uint_as_float(hv.y & 0xFFFF0000u);
}

// ---------------------------------------------------------------------------
// Dual GEMM layer a: h = x@K1 (bf16), p = x@K2 + b (f32).  x:[n,128]
// ---------------------------------------------------------------------------
__device__ __forceinline__ void gemm_row_f128(const float* xr,
                                              const float* __restrict__ K,
                                              float* acc) {
    for (int k = 0; k < 128; ++k) {
        float xv = xr[k];
        const float* Kr = K + k * 32;
        #pragma unroll
        for (int c = 0; c < 32; ++c) acc[c] = fmaf(xv, Kr[c], acc[c]);
    }
}

__global__ __launch_bounds__(128) void gemm_dual_a(
    const float* __restrict__ x, const float* __restrict__ K1,
    const float* __restrict__ K2, const float* __restrict__ bias,
    ushort* __restrict__ h, float* __restrict__ p, int n)
{
    __shared__ float xs[64 * 129];
    const int base = blockIdx.x * 64;

    for (int i = threadIdx.x; i < 64 * 32; i += 128) {
        int r = i >> 5, c4 = i & 31;
        int node = base + r;
        float4 v = make_float4(0.f, 0.f, 0.f, 0.f);
        if (node < n) v = *(const float4*)(x + (size_t)node * 128 + c4 * 4);
        float* d = &xs[r * 129 + c4 * 4];
        d[0] = v.x; d[1] = v.y; d[2] = v.z; d[3] = v.w;
    }
    __syncthreads();

    const int nl = threadIdx.x & 63;
    const int node = base + nl;
    if (node >= n) return;

    float acc[32];
    #pragma unroll
    for (int c = 0; c < 32; ++c) acc[c] = 0.f;

    const float* xr = &xs[nl * 129];
    if (threadIdx.x < 64) {
        gemm_row_f128(xr, K1, acc);
        store_row_bf16(h + (size_t)node * 32, acc);
    } else {
        gemm_row_f128(xr, K2, acc);
        #pragma unroll
        for (int c = 0; c < 32; ++c) acc[c] += bias[c];
        float* out = p + (size_t)node * 32;
        #pragma unroll
        for (int c4 = 0; c4 < 8; ++c4)
            *(float4*)(out + c4 * 4) = make_float4(acc[c4*4], acc[c4*4+1], acc[c4*4+2], acc[c4*4+3]);
    }
}

// ---------------------------------------------------------------------------
// Dual GEMM layer b: reads x1:[n,32] f32; h out bf16, p out f32.
// ---------------------------------------------------------------------------
__device__ __forceinline__ void gemm_row_f32(const float* xr,
                                             const float* __restrict__ K,
                                             float* acc) {
    for (int k = 0; k < 32; ++k) {
        float xv = xr[k];
        const float* Kr = K + k * 32;
        #pragma unroll
        for (int c = 0; c < 32; ++c) acc[c] = fmaf(xv, Kr[c], acc[c]);
    }
}

__global__ __launch_bounds__(128) void gemm_dual_b(
    const float* __restrict__ x1,
    const float* __restrict__ K1, const float* __restrict__ K2,
    const float* __restrict__ bias,
    ushort* __restrict__ h, float* __restrict__ p, int n)
{
    __shared__ float xs[64 * 33];
    const int base = blockIdx.x * 64;

    for (int i = threadIdx.x; i < 64 * 8; i += 128) {
        int r = i >> 3, c4 = i & 7;
        int node = base + r;
        float4 a = make_float4(0.f, 0.f, 0.f, 0.f);
        if (node < n) a = *(const float4*)(x1 + (size_t)node * 32 + c4 * 4);
        float* d = &xs[r * 33 + c4 * 4];
        d[0] = a.x; d[1] = a.y; d[2] = a.z; d[3] = a.w;
    }
    __syncthreads();

    const int nl = threadIdx.x & 63;
    const int node = base + nl;
    if (node >= n) return;

    float acc[32];
    #pragma unroll
    for (int c = 0; c < 32; ++c) acc[c] = 0.f;

    const float* xr = &xs[nl * 33];
    if (threadIdx.x < 64) {
        gemm_row_f32(xr, K1, acc);
        store_row_bf16(h + (size_t)node * 32, acc);
    } else {
        gemm_row_f32(xr, K2, acc);
        #pragma unroll
        for (int c = 0; c < 32; ++c) acc[c] += bias[c];
        float* out = p + (size_t)node * 32;
        #pragma unroll
        for (int c4 = 0; c4 < 8; ++c4)
            *(float4*)(out + c4 * 4) = make_float4(acc[c4*4], acc[c4*4+1], acc[c4*4+2], acc[c4*4+3]);
    }
}

// ---------------------------------------------------------------------------
// CSR gather core: 8 threads/node, bf16 h rows (64 B/edge), 4-way unroll.
// ---------------------------------------------------------------------------
__device__ __forceinline__ float4 gather_node(
    const int* __restrict__ row, const ull* __restrict__ epack,
    const ushort* __restrict__ h, int node, int q)
{
    int r0 = row[node], r1 = row[node + 1];
    float4 a = make_float4(0.f, 0.f, 0.f, 0.f);
    float4 b = make_float4(0.f, 0.f, 0.f, 0.f);
    int i = r0;
    for (; i + 3 < r1; i += 4) {
        ull p0 = epack[i],     p1 = epack[i + 1];
        ull p2 = epack[i + 2], p3 = epack[i + 3];
        uint2 h0 = *(const uint2*)(h + (size_t)(p0 & 0xFFFFFu) * 32 + q * 4);
        uint2 h1 = *(const uint2*)(h + (size_t)(p1 & 0xFFFFFu) * 32 + q * 4);
        uint2 h2 = *(const uint2*)(h + (size_t)(p2 & 0xFFFFFu) * 32 + q * 4);
        uint2 h3 = *(const uint2*)(h + (size_t)(p3 & 0xFFFFFu) * 32 + q * 4);
        float w0 = __uint_as_float((uint)(p0 >> 32));
        float w1 = __uint_as_float((uint)(p1 >> 32));
        float w2 = __uint_as_float((uint)(p2 >> 32));
        float w3 = __uint_as_float((uint)(p3 >> 32));
        float f0, f1, f2, f3;
        bf16x4_decode(h0, f0, f1, f2, f3);
        a.x = fmaf(w0, f0, a.x); a.y = fmaf(w0, f1, a.y);
        a.z = fmaf(w0, f2, a.z); a.w = fmaf(w0, f3, a.w);
        bf16x4_decode(h1, f0, f1, f2, f3);
        b.x = fmaf(w1, f0, b.x); b.y = fmaf(w1, f1, b.y);
        b.z = fmaf(w1, f2, b.z); b.w = fmaf(w1, f3, b.w);
        bf16x4_decode(h2, f0, f1, f2, f3);
        a.x = fmaf(w2, f0, a.x); a.y = fmaf(w2, f1, a.y);
        a.z = fmaf(w2, f2, a.z); a.w = fmaf(w2, f3, a.w);
        bf16x4_decode(h3, f0, f1, f2, f3);
        b.x = fmaf(w3, f0, b.x); b.y = fmaf(w3, f1, b.y);
        b.z = fmaf(w3, f2, b.z); b.w = fmaf(w3, f3, b.w);
    }
    for (; i < r1; ++i) {
        ull p0 = epack[i];
        uint2 h0 = *(const uint2*)(h + (size_t)(p0 & 0xFFFFFu) * 32 + q * 4);
        float w0 = __uint_as_float((uint)(p0 >> 32));
        float f0, f1, f2, f3;
        bf16x4_decode(h0, f0, f1, f2, f3);
        a.x = fmaf(w0, f0, a.x); a.y = fmaf(w0, f1, a.y);
        a.z = fmaf(w0, f2, a.z); a.w = fmaf(w0, f3, a.w);
    }
    a.x += b.x; a.y += b.y; a.z += b.z; a.w += b.w;
    return a;
}

__global__ __launch_bounds__(256) void gather_x1_kernel(
    const int* __restrict__ row, const ull* __restrict__ epack,
    const ushort* __restrict__ h, const float* __restrict__ p,
    float* __restrict__ x1, int n)
{
    const int q = threadIdx.x & 7;
    const int node = blockIdx.x * 32 + (threadIdx.x >> 3);
    if (node >= n) return;
    float4 acc = gather_node(row, epack, h, node, q);
    const float4 pv = *(const float4*)(p + (size_t)node * 32 + q * 4);
    float4 o;
    o.x = fmaxf(acc.x + pv.x, 0.f);
    o.y = fmaxf(acc.y + pv.y, 0.f);
    o.z = fmaxf(acc.z + pv.z, 0.f);
    o.w = fmaxf(acc.w + pv.w, 0.f);
    *(float4*)(x1 + (size_t)node * 32 + q * 4) = o;
}

__global__ __launch_bounds__(256) void gather_pool_kernel(
    const int* __restrict__ row, const ull* __restrict__ epack,
    const ushort* __restrict__ h, const float* __restrict__ p,
    float* __restrict__ pooled, int n)
{
    const int q = threadIdx.x & 7;
    const int node = blockIdx.x * 32 + (threadIdx.x >> 3);

    float4 o = make_float4(0.f, 0.f, 0.f, 0.f);
    if (node < n) {
        float4 acc = gather_node(row, epack, h, node, q);
        const float4 pv = *(const float4*)(p + (size_t)node * 32 + q * 4);
        o.x = fmaxf(acc.x + pv.x, 0.f);
        o.y = fmaxf(acc.y + pv.y, 0.f);
        o.z = fmaxf(acc.z + pv.z, 0.f);
        o.w = fmaxf(acc.w + pv.w, 0.f);
    }
    __shared__ float red[256][4];
    red[threadIdx.x][0] = o.x; red[threadIdx.x][1] = o.y;
    red[threadIdx.x][2] = o.z; red[threadIdx.x][3] = o.w;
    __syncthreads();
    if (threadIdx.x < 32) {
        const int c = threadIdx.x;
        const int cq = c >> 2, cj = c & 3;
        float s = 0.f;
        #pragma unroll
        for (int l = 0; l < 32; ++l) s += red[l * 8 + cq][cj];
        unsafeAtomicAdd(&pooled[c], s);
    }
}

// ---------------------------------------------------------------------------
// Fallback (ws too small / nb too large): atomic scatter path (bf16 h).
// ---------------------------------------------------------------------------
__global__ __launch_bounds__(256) void edge_scatter(
    const int* __restrict__ src, const int* __restrict__ dst,
    const float* __restrict__ w, const ushort* __restrict__ h,
    float* __restrict__ agg, int e)
{
    int t = blockIdx.x * 256 + threadIdx.x;
    int eid = t >> 3, q = t & 7;
    if (eid >= e) return;
    int s = src[eid];
    int d = dst[eid];
    float wv = w[eid];
    uint2 hv = *(const uint2*)(h + (size_t)s * 32 + q * 4);
    float f0, f1, f2, f3;
    bf16x4_decode(hv, f0, f1, f2, f3);
    float* ap = agg + (size_t)d * 32 + q * 4;
    unsafeAtomicAdd(ap + 0, f0 * wv);
    unsafeAtomicAdd(ap + 1, f1 * wv);
    unsafeAtomicAdd(ap + 2, f2 * wv);
    unsafeAtomicAdd(ap + 3, f3 * wv);
}

__global__ __launch_bounds__(256) void relu_add_kernel(
    const float* __restrict__ a, const float* __restrict__ b,
    float* __restrict__ o, size_t m)
{
    size_t i = (size_t)blockIdx.x * 256 + threadIdx.x;
    if (i < m) o[i] = fmaxf(a[i] + b[i], 0.f);
}

__global__ __launch_bounds__(256) void pool_kernel(
    const float* __restrict__ p, const float* __restrict__ agg,
    float* __restrict__ pooled, int n)
{
    const int ch = threadIdx.x & 31;
    const int r  = threadIdx.x >> 5;
    float acc = 0.f;
    for (int node = blockIdx.x * 8 + r; node < n; node += gridDim.x * 8) {
        size_t idx = (size_t)node * 32 + ch;
        acc += fmaxf(p[idx] + agg[idx], 0.f);
    }
    __shared__ float red[256];
    red[threadIdx.x] = acc;
    __syncthreads();
    if (threadIdx.x < 32) {
        float s = 0.f;
        #pragma unroll
        for (int i = 0; i < 8; ++i) s += red[i * 32 + ch];
        unsafeAtomicAdd(&pooled[ch], s);
    }
}

__global__ void dense_kernel(
    const float* __restrict__ pooled,
    const float* __restrict__ Wd1, const float* __restrict__ bd1,
    const float* __restrict__ Wd2, const float* __restrict__ bd2,
    float* __restrict__ out)
{
    int j = threadIdx.x;
    float t = 0.f;
    if (j < 24) {
        t = bd1[j];
        #pragma unroll
        for (int c = 0; c < 32; ++c) t = fmaf(pooled[c], Wd1[c * 24 + j], t);
        t *= Wd2[j];
    }
    #pragma unroll
    for (int off = 32; off > 0; off >>= 1) t += __shfl_down(t, off, 64);
    if (j == 0) out[0] = t + bd2[0];
}

extern "C" void kernel_launch(void* const* d_in, const int* in_sizes, int n_in,
                              void* d_out, int out_size, void* d_ws, size_t ws_size,
                              hipStream_t stream) {
    const float* x   = (const float*)d_in[0];
    const int*   esrc= (const int*)d_in[1];
    const int*   edst= (const int*)d_in[2];
    const float* ew  = (const float*)d_in[3];
    const float* K1a = (const float*)d_in[4];
    const float* K2a = (const float*)d_in[5];
    const float* ba  = (const float*)d_in[6];
    const float* K1b = (const float*)d_in[7];
    const float* K2b = (const float*)d_in[8];
    const float* bb  = (const float*)d_in[9];
    const float* Wd1 = (const float*)d_in[10];
    const float* bd1 = (const float*)d_in[11];
    const float* Wd2 = (const float*)d_in[12];
    const float* bd2 = (const float*)d_in[13];

    const int n = in_sizes[0] / 128;   // 100000
    const int e = in_sizes[1];         // 3200000
    const size_t nc = (size_t)n * 32;
    const int nb = (n + NPB - 1) / NPB;            // 391
    const int nruns = (e + CHUNK - 1) / CHUNK;     // 391

    // ws layout:
    //   epack [e] ull                 (persists through gathers)
    //   etmp  [e] ull  -> reused as A_bf16[nc] + B_f32[nc] after sort_buckets
    //   Cg    [nc] f32
    //   pooled [32] f32
    //   row   [n+1] int
    //   bucket_cnt [nb] int | bucket_base [nb+1] int
    //   runoff [nruns*(nb+1)] int
    const size_t ab_bytes = nc * 2 + nc * 4;   // A bf16 + B f32
    const size_t etmp_bytes = ((size_t)e * 8 > ab_bytes) ? (size_t)e * 8 : ab_bytes;
    const size_t need = (size_t)e * 8 + etmp_bytes + nc * 4 + 32 * 4
                      + (size_t)(n + 1) * 4 + (size_t)nb * 4 + (size_t)(nb + 1) * 4
                      + (size_t)nruns * (nb + 1) * 4;

    const int gemm_blocks   = (n + 63) / 64;
    const int gather_blocks = (n + 31) / 32;

    if (ws_size >= need && nb <= NBMAX) {
        char* wp = (char*)d_ws;
        ull* epack = (ull*)wp;                wp += (size_t)e * 8;
        ull* etmp  = (ull*)wp;
        ushort* A = (ushort*)etmp;            // bf16 h, aliases etmp after sort
        float* B = (float*)(A + nc);          wp += etmp_bytes;
        float* Cg = (float*)wp;               wp += nc * 4;
        float* pooled = (float*)wp;           wp += 32 * 4;
        int* row = (int*)wp;                  wp += (size_t)(n + 1) * 4;
        int* bucket_cnt = (int*)wp;           wp += (size_t)nb * 4;
        int* bucket_base = (int*)wp;          wp += (size_t)(nb + 1) * 4;
        int* runoff = (int*)wp;

        hipMemsetAsync(bucket_cnt, 0, (size_t)nb * 4, stream);
        hipMemsetAsync(pooled, 0, 32 * 4, stream);

        build_runs_kernel<<<nruns, 512, 0, stream>>>(esrc, edst, ew, etmp, runoff,
                                                     bucket_cnt, e, nruns, nb);
        bucket_scan_kernel<<<1, 512, 0, stream>>>(bucket_cnt, bucket_base, nb, e);
        sort_buckets_kernel<<<nb, 512, 0, stream>>>(etmp, runoff, bucket_base,
                                                    epack, row, n, e, nruns, nb);
        // etmp is dead now; its storage becomes A (bf16), B (f32).
        gemm_dual_a<<<gemm_blocks, 128, 0, stream>>>(x, K1a, K2a, ba, A, B, n);
        gather_x1_kernel<<<gather_blocks, 256, 0, stream>>>(row, epack, A, B, Cg, n);
        gemm_dual_b<<<gemm_blocks, 128, 0, stream>>>(Cg, K1b, K2b, bb, A, B, n);
        gather_pool_kernel<<<gather_blocks, 256, 0, stream>>>(row, epack, A, B, pooled, n);
        dense_kernel<<<1, 64, 0, stream>>>(pooled, Wd1, bd1, Wd2, bd2, (float*)d_out);
    } else {
        // fallback: atomic scatter path
        ushort* A     = (ushort*)d_ws;             // bf16 h (nc*2 bytes)
        float* B      = (float*)(A + 2 * nc);      // keep region sizes generous
        float* Cg     = B + nc;
        float* pooled = Cg + nc;
        const int edge_blocks_8 = (int)(((long long)e * 8 + 255) / 256);

        hipMemsetAsync(Cg, 0, nc * 4, stream);
        gemm_dual_a<<<gemm_blocks, 128, 0, stream>>>(x, K1a, K2a, ba, A, B, n);
        edge_scatter<<<edge_blocks_8, 256, 0, stream>>>(esrc, edst, ew, A, Cg, e);
        relu_add_kernel<<<(int)((nc + 255) / 256), 256, 0, stream>>>(B, Cg, B, nc);
        gemm_dual_b<<<gemm_blocks, 128, 0, stream>>>(B, K1b, K2b, bb, A, Cg, n);
        hipMemsetAsync(B, 0, nc * 4, stream);
        edge_scatter<<<edge_blocks_8, 256, 0, stream>>>(esrc, edst, ew, A, B, e);
        hipMemsetAsync(pooled, 0, 32 * 4, stream);
        pool_kernel<<<1024, 256, 0, stream>>>(Cg, B, pooled, n);
        dense_kernel<<<1, 64, 0, stream>>>(pooled, Wd1, bd1, Wd2, bd2, (float*)d_out);
    }
}

// Round 7
// 223.997 us; speedup vs baseline: 6.8355x; 1.2159x over previous
//
#include <hip/hip_runtime.h>
#include <hip/hip_bf16.h>

typedef unsigned long long ull;
typedef unsigned int uint;
typedef unsigned short ushort;

using bf16x8 = __attribute__((ext_vector_type(8))) short;
using f32x4  = __attribute__((ext_vector_type(4))) float;

// Problem constants: N=100000 nodes, E=3200000 edges, F=128, C=32, H=24
//
// Pipeline:
//   0. prep_weights: [K1|K2] -> bf16, transposed [col][k]
//   1. build_runs / bucket_scan / sort_buckets: dst-sorted epack + CSR row[]
//   2. gemm_mfma_a:  h_a = bf16(x@K1a), p_a = x@K2a + ba   (MFMA 16x16x32)
//   3. gather_x1:    x1 = bf16(relu(csr_gather(h_a) + p_a))
//   4. gemm_mfma_b:  h_b = bf16(x1@K1b), p_b = x1@K2b + bb (MFMA, K=32)
//   5. gather_pool:  pooled += relu(csr_gather(h_b) + p_b)
//   6. dense epilogue
//
// record: low = src | (dst&255)<<20 ; high = f32 bits of w   (src < 2^20)

#define CHUNK    8192
#define NPB      256
#define NBMAX    512
#define STAGECAP 9216   // 72 KB

__device__ __forceinline__ ushort f2bf(float f) {
    __hip_bfloat16 b = __float2bfloat16(f);
    return *reinterpret_cast<ushort*>(&b);
}
__device__ __forceinline__ uint pack2(float a, float b) {
    return (uint)f2bf(a) | ((uint)f2bf(b) << 16);
}
__device__ __forceinline__ void bf16x4_decode(uint2 hv, float& f0, float& f1,
                                              float& f2, float& f3) {
    f0 = __uint_as_float(hv.x << 16);
    f1 = __uint_as_float(hv.x & 0xFFFF0000u);
    f2 = __uint_as_float(hv.y << 16);
    f3 = __uint_as_float(hv.y & 0xFFFF0000u);
}

// ---------------------------------------------------------------------------
// Phase 0: weight prep. Kca[col][k] (64x128), Kcb[col][k] (64x32), bf16.
// ---------------------------------------------------------------------------
__global__ __launch_bounds__(256) void prep_weights(
    const float* __restrict__ K1a, const float* __restrict__ K2a,
    const float* __restrict__ K1b, const float* __restrict__ K2b,
    ushort* __restrict__ Kca, ushort* __restrict__ Kcb)
{
    int t = blockIdx.x * 256 + threadIdx.x;
    if (t < 8192) {
        int col = t >> 7, k = t & 127;
        float v = (col < 32) ? K1a[k * 32 + col] : K2a[k * 32 + col - 32];
        Kca[col * 128 + k] = f2bf(v);
    }
    if (t < 2048) {
        int col = t >> 5, k = t & 31;
        float v = (col < 32) ? K1b[k * 32 + col] : K2b[k * 32 + col - 32];
        Kcb[col * 32 + k] = f2bf(v);
    }
}

// ---------------------------------------------------------------------------
// Phase 1: LDS-staged counting sort of each 8192-edge chunk by bucket.
// ---------------------------------------------------------------------------
__global__ __launch_bounds__(512) void build_runs_kernel(
    const int* __restrict__ src, const int* __restrict__ dst,
    const float* __restrict__ w,
    ull* __restrict__ etmp, int* __restrict__ runoff,
    int* __restrict__ bucket_cnt, int e, int nruns, int nb)
{
    __shared__ ull stage[CHUNK];      // 64 KB
    __shared__ int hist[NBMAX];
    __shared__ int scn[NBMAX];
    const int r = blockIdx.x, tid = threadIdx.x;
    const int base = r * CHUNK;
    const int cnt = min(CHUNK, e - base);

    hist[tid] = 0;
    __syncthreads();

    int dreg[CHUNK / 512];
    #pragma unroll
    for (int k = 0; k < CHUNK / 512; ++k) {
        int i = tid + k * 512;
        int d = (i < cnt) ? dst[base + i] : -1;
        dreg[k] = d;
        if (d >= 0) atomicAdd(&hist[d >> 8], 1);
    }
    __syncthreads();

    int v = hist[tid];
    scn[tid] = v;
    __syncthreads();
    for (int off = 1; off < NBMAX; off <<= 1) {
        int u = (tid >= off) ? scn[tid - off] : 0;
        __syncthreads();
        scn[tid] += u;
        __syncthreads();
    }
    const int ex = scn[tid] - v;
    if (tid < nb && v) atomicAdd(&bucket_cnt[tid], v);
    hist[tid] = ex;                   // becomes cursor
    if (tid <= nb) runoff[(size_t)r * (nb + 1) + tid] = base + ex;
    __syncthreads();

    #pragma unroll
    for (int k = 0; k < CHUNK / 512; ++k) {
        int i = tid + k * 512;
        int d = dreg[k];
        if (d >= 0) {
            int pos = atomicAdd(&hist[d >> 8], 1);
            unsigned lo = (unsigned)src[base + i] | ((unsigned)(d & 255) << 20);
            stage[pos] = (ull)lo | ((ull)__float_as_uint(w[base + i]) << 32);
        }
    }
    __syncthreads();

    for (int i = tid; i < cnt; i += 512) etmp[base + i] = stage[i];
}

__global__ __launch_bounds__(512) void bucket_scan_kernel(
    const int* __restrict__ cnt, int* __restrict__ basep, int nb, int e)
{
    __shared__ int s[512];
    int t = threadIdx.x;
    int v = (t < nb) ? cnt[t] : 0;
    s[t] = v; __syncthreads();
    for (int off = 1; off < 512; off <<= 1) {
        int u = (t >= off) ? s[t - off] : 0;
        __syncthreads(); s[t] += u; __syncthreads();
    }
    if (t < nb) basep[t] = s[t] - v;
    if (t == 0) basep[nb] = e;
}

// ---------------------------------------------------------------------------
// Phase 3: fine sort per bucket (LDS stage, coalesced copy-out).
// ---------------------------------------------------------------------------
__global__ __launch_bounds__(512) void sort_buckets_kernel(
    const ull* __restrict__ etmp, const int* __restrict__ runoff,
    const int* __restrict__ bbase,
    ull* __restrict__ epack, int* __restrict__ row,
    int n, int e, int nruns, int nb)
{
    __shared__ ull stage[STAGECAP];   // 72 KB
    __shared__ int hist[NPB];
    __shared__ int scn[NPB];
    __shared__ int cur[NPB];
    const int b = blockIdx.x, tid = threadIdx.x;
    const int base0 = bbase[b];
    const int cnt = bbase[b + 1] - base0;

    if (tid < NPB) hist[tid] = 0;
    __syncthreads();

    const int stream = tid >> 3, sub = tid & 7;   // 64 streams x 8 lanes
    const int* rs = runoff;

    for (int r = stream; r < nruns; r += 64) {
        int s0 = rs[(size_t)r * (nb + 1) + b];
        int s1 = rs[(size_t)r * (nb + 1) + b + 1];
        for (int i = s0 + sub; i < s1; i += 8)
            atomicAdd(&hist[(int)((etmp[i] >> 20) & 255u)], 1);
    }
    __syncthreads();

    int v = (tid < NPB) ? hist[tid] : 0;
    if (tid < NPB) scn[tid] = v;
    __syncthreads();
    for (int off = 1; off < NPB; off <<= 1) {
        int u = (tid >= off && tid < NPB) ? scn[tid - off] : 0;
        __syncthreads();
        if (tid < NPB) scn[tid] += u;
        __syncthreads();
    }
    if (tid < NPB) {
        int ex = scn[tid] - v;
        cur[tid] = ex;
        int node = b * NPB + tid;
        if (node < n) row[node] = base0 + ex;
    }
    if (b == nb - 1 && tid == 0) row[n] = e;
    __syncthreads();

    if (cnt <= STAGECAP) {
        for (int r = stream; r < nruns; r += 64) {
            int s0 = rs[(size_t)r * (nb + 1) + b];
            int s1 = rs[(size_t)r * (nb + 1) + b + 1];
            for (int i = s0 + sub; i < s1; i += 8) {
                ull pk = etmp[i];
                int pos = atomicAdd(&cur[(int)((pk >> 20) & 255u)], 1);
                stage[pos] = pk;
            }
        }
        __syncthreads();
        for (int i = tid; i < cnt; i += 512) epack[(size_t)base0 + i] = stage[i];
    } else {
        for (int r = stream; r < nruns; r += 64) {
            int s0 = rs[(size_t)r * (nb + 1) + b];
            int s1 = rs[(size_t)r * (nb + 1) + b + 1];
            for (int i = s0 + sub; i < s1; i += 8) {
                ull pk = etmp[i];
                int pos = atomicAdd(&cur[(int)((pk >> 20) & 255u)], 1);
                epack[(size_t)base0 + pos] = pk;
            }
        }
    }
}

// ---------------------------------------------------------------------------
// MFMA dual GEMM layer a: [64 nodes] x [128 K] @ [128][64 cols = K1a|K2a].
// 4 waves; wave w owns nodes w*16..w*16+15, all 64 cols (4 N-tiles).
// A staged in LDS as bf16 (pad 136/row, 2-way banks, 16B aligned).
// C mapping (m89-verified): col=lane&15, row=(lane>>4)*4+reg.
// ---------------------------------------------------------------------------
__global__ __launch_bounds__(256) void gemm_mfma_a(
    const float* __restrict__ x, const ushort* __restrict__ Kca,
    const float* __restrict__ bias,
    ushort* __restrict__ h, float* __restrict__ p, int n)
{
    __shared__ ushort xs[64 * 136];   // 17408 B
    const int tid = threadIdx.x;
    const int base = blockIdx.x * 64;

    for (int idx = tid; idx < 64 * 16; idx += 256) {
        int nl = idx >> 4, c8 = idx & 15;
        int node = base + nl;
        float4 v0 = make_float4(0.f, 0.f, 0.f, 0.f);
        float4 v1 = v0;
        if (node < n) {
            const float* xp = x + (size_t)node * 128 + c8 * 8;
            v0 = *(const float4*)xp;
            v1 = *(const float4*)(xp + 4);
        }
        uint4 u;
        u.x = pack2(v0.x, v0.y); u.y = pack2(v0.z, v0.w);
        u.z = pack2(v1.x, v1.y); u.w = pack2(v1.z, v1.w);
        *(uint4*)&xs[nl * 136 + c8 * 8] = u;
    }
    __syncthreads();

    const int lane = tid & 63, w = tid >> 6;
    const int r15 = lane & 15, g = lane >> 4;
    const int nbase = w * 16;

    f32x4 acc[4] = {{0.f,0.f,0.f,0.f},{0.f,0.f,0.f,0.f},
                    {0.f,0.f,0.f,0.f},{0.f,0.f,0.f,0.f}};

    #pragma unroll
    for (int kk = 0; kk < 4; ++kk) {
        bf16x8 af = *(const bf16x8*)&xs[(nbase + r15) * 136 + kk * 32 + g * 8];
        #pragma unroll
        for (int t = 0; t < 4; ++t) {
            bf16x8 bfr = *(const bf16x8*)&Kca[(size_t)(t * 16 + r15) * 128 + kk * 32 + g * 8];
            acc[t] = __builtin_amdgcn_mfma_f32_16x16x32_bf16(af, bfr, acc[t], 0, 0, 0);
        }
    }

    #pragma unroll
    for (int t = 0; t < 4; ++t) {
        int col = t * 16 + r15;
        float bv = (col >= 32) ? bias[col - 32] : 0.f;
        #pragma unroll
        for (int i = 0; i < 4; ++i) {
            int node = base + nbase + g * 4 + i;
            if (node < n) {
                float v = acc[t][i];
                if (col < 32) h[(size_t)node * 32 + col] = f2bf(v);
                else          p[(size_t)node * 32 + col - 32] = v + bv;
            }
        }
    }
}

// ---------------------------------------------------------------------------
// MFMA dual GEMM layer b: [64 nodes] x [32 K] @ [32][64 cols]. K=32 = 1 step.
// x1 input already bf16.
// ---------------------------------------------------------------------------
__global__ __launch_bounds__(256) void gemm_mfma_b(
    const ushort* __restrict__ x1, const ushort* __restrict__ Kcb,
    const float* __restrict__ bias,
    ushort* __restrict__ h, float* __restrict__ p, int n)
{
    __shared__ ushort xs[64 * 40];    // 5120 B
    const int tid = threadIdx.x;
    const int base = blockIdx.x * 64;

    {
        int nl = tid >> 2, c8 = tid & 3;
        int node = base + nl;
        uint4 u = make_uint4(0u, 0u, 0u, 0u);
        if (node < n) u = *(const uint4*)(x1 + (size_t)node * 32 + c8 * 8);
        *(uint4*)&xs[nl * 40 + c8 * 8] = u;
    }
    __syncthreads();

    const int lane = tid & 63, w = tid >> 6;
    const int r15 = lane & 15, g = lane >> 4;
    const int nbase = w * 16;

    f32x4 acc[4] = {{0.f,0.f,0.f,0.f},{0.f,0.f,0.f,0.f},
                    {0.f,0.f,0.f,0.f},{0.f,0.f,0.f,0.f}};

    bf16x8 af = *(const bf16x8*)&xs[(nbase + r15) * 40 + g * 8];
    #pragma unroll
    for (int t = 0; t < 4; ++t) {
        bf16x8 bfr = *(const bf16x8*)&Kcb[(size_t)(t * 16 + r15) * 32 + g * 8];
        acc[t] = __builtin_amdgcn_mfma_f32_16x16x32_bf16(af, bfr, acc[t], 0, 0, 0);
    }

    #pragma unroll
    for (int t = 0; t < 4; ++t) {
        int col = t * 16 + r15;
        float bv = (col >= 32) ? bias[col - 32] : 0.f;
        #pragma unroll
        for (int i = 0; i < 4; ++i) {
            int node = base + nbase + g * 4 + i;
            if (node < n) {
                float v = acc[t][i];
                if (col < 32) h[(size_t)node * 32 + col] = f2bf(v);
                else          p[(size_t)node * 32 + col - 32] = v + bv;
            }
        }
    }
}

// ---------------------------------------------------------------------------
// CSR gather core: 8 threads/node, bf16 h rows (64 B/edge), 4-way unroll.
// ---------------------------------------------------------------------------
__device__ __forceinline__ float4 gather_node(
    const int* __restrict__ row, const ull* __restrict__ epack,
    const ushort* __restrict__ h, int node, int q)
{
    int r0 = row[node], r1 = row[node + 1];
    float4 a = make_float4(0.f, 0.f, 0.f, 0.f);
    float4 b = make_float4(0.f, 0.f, 0.f, 0.f);
    int i = r0;
    for (; i + 3 < r1; i += 4) {
        ull p0 = epack[i],     p1 = epack[i + 1];
        ull p2 = epack[i + 2], p3 = epack[i + 3];
        uint2 h0 = *(const uint2*)(h + (size_t)(p0 & 0xFFFFFu) * 32 + q * 4);
        uint2 h1 = *(const uint2*)(h + (size_t)(p1 & 0xFFFFFu) * 32 + q * 4);
        uint2 h2 = *(const uint2*)(h + (size_t)(p2 & 0xFFFFFu) * 32 + q * 4);
        uint2 h3 = *(const uint2*)(h + (size_t)(p3 & 0xFFFFFu) * 32 + q * 4);
        float w0 = __uint_as_float((uint)(p0 >> 32));
        float w1 = __uint_as_float((uint)(p1 >> 32));
        float w2 = __uint_as_float((uint)(p2 >> 32));
        float w3 = __uint_as_float((uint)(p3 >> 32));
        float f0, f1, f2, f3;
        bf16x4_decode(h0, f0, f1, f2, f3);
        a.x = fmaf(w0, f0, a.x); a.y = fmaf(w0, f1, a.y);
        a.z = fmaf(w0, f2, a.z); a.w = fmaf(w0, f3, a.w);
        bf16x4_decode(h1, f0, f1, f2, f3);
        b.x = fmaf(w1, f0, b.x); b.y = fmaf(w1, f1, b.y);
        b.z = fmaf(w1, f2, b.z); b.w = fmaf(w1, f3, b.w);
        bf16x4_decode(h2, f0, f1, f2, f3);
        a.x = fmaf(w2, f0, a.x); a.y = fmaf(w2, f1, a.y);
        a.z = fmaf(w2, f2, a.z); a.w = fmaf(w2, f3, a.w);
        bf16x4_decode(h3, f0, f1, f2, f3);
        b.x = fmaf(w3, f0, b.x); b.y = fmaf(w3, f1, b.y);
        b.z = fmaf(w3, f2, b.z); b.w = fmaf(w3, f3, b.w);
    }
    for (; i < r1; ++i) {
        ull p0 = epack[i];
        uint2 h0 = *(const uint2*)(h + (size_t)(p0 & 0xFFFFFu) * 32 + q * 4);
        float w0 = __uint_as_float((uint)(p0 >> 32));
        float f0, f1, f2, f3;
        bf16x4_decode(h0, f0, f1, f2, f3);
        a.x = fmaf(w0, f0, a.x); a.y = fmaf(w0, f1, a.y);
        a.z = fmaf(w0, f2, a.z); a.w = fmaf(w0, f3, a.w);
    }
    a.x += b.x; a.y += b.y; a.z += b.z; a.w += b.w;
    return a;
}

// x1 = bf16(relu(agg + p)), coalesced uint2 stores.
__global__ __launch_bounds__(256) void gather_x1_kernel(
    const int* __restrict__ row, const ull* __restrict__ epack,
    const ushort* __restrict__ h, const float* __restrict__ p,
    ushort* __restrict__ x1, int n)
{
    const int q = threadIdx.x & 7;
    const int node = blockIdx.x * 32 + (threadIdx.x >> 3);
    if (node >= n) return;
    float4 acc = gather_node(row, epack, h, node, q);
    const float4 pv = *(const float4*)(p + (size_t)node * 32 + q * 4);
    float4 o;
    o.x = fmaxf(acc.x + pv.x, 0.f);
    o.y = fmaxf(acc.y + pv.y, 0.f);
    o.z = fmaxf(acc.z + pv.z, 0.f);
    o.w = fmaxf(acc.w + pv.w, 0.f);
    uint2 u;
    u.x = pack2(o.x, o.y);
    u.y = pack2(o.z, o.w);
    *(uint2*)(x1 + (size_t)node * 32 + q * 4) = u;
}

__global__ __launch_bounds__(256) void gather_pool_kernel(
    const int* __restrict__ row, const ull* __restrict__ epack,
    const ushort* __restrict__ h, const float* __restrict__ p,
    float* __restrict__ pooled, int n)
{
    const int q = threadIdx.x & 7;
    const int node = blockIdx.x * 32 + (threadIdx.x >> 3);

    float4 o = make_float4(0.f, 0.f, 0.f, 0.f);
    if (node < n) {
        float4 acc = gather_node(row, epack, h, node, q);
        const float4 pv = *(const float4*)(p + (size_t)node * 32 + q * 4);
        o.x = fmaxf(acc.x + pv.x, 0.f);
        o.y = fmaxf(acc.y + pv.y, 0.f);
        o.z = fmaxf(acc.z + pv.z, 0.f);
        o.w = fmaxf(acc.w + pv.w, 0.f);
    }
    __shared__ float red[256][4];
    red[threadIdx.x][0] = o.x; red[threadIdx.x][1] = o.y;
    red[threadIdx.x][2] = o.z; red[threadIdx.x][3] = o.w;
    __syncthreads();
    if (threadIdx.x < 32) {
        const int c = threadIdx.x;
        const int cq = c >> 2, cj = c & 3;
        float s = 0.f;
        #pragma unroll
        for (int l = 0; l < 32; ++l) s += red[l * 8 + cq][cj];
        unsafeAtomicAdd(&pooled[c], s);
    }
}

// ---------------------------------------------------------------------------
// Fallback path kernels (f32 VALU GEMMs, atomic scatter) — only if ws small.
// ---------------------------------------------------------------------------
__device__ __forceinline__ void store_row_bf16(ushort* out, const float* acc) {
    uint u[16];
    #pragma unroll
    for (int k = 0; k < 16; ++k) u[k] = pack2(acc[2 * k], acc[2 * k + 1]);
    uint4* o = (uint4*)out;
    o[0] = make_uint4(u[0], u[1], u[2], u[3]);
    o[1] = make_uint4(u[4], u[5], u[6], u[7]);
    o[2] = make_uint4(u[8], u[9], u[10], u[11]);
    o[3] = make_uint4(u[12], u[13], u[14], u[15]);
}

__global__ __launch_bounds__(128) void gemm_f32_a(
    const float* __restrict__ x, const float* __restrict__ K1,
    const float* __restrict__ K2, const float* __restrict__ bias,
    ushort* __restrict__ h, float* __restrict__ p, int n)
{
    __shared__ float xs[64 * 129];
    const int base = blockIdx.x * 64;
    for (int i = threadIdx.x; i < 64 * 32; i += 128) {
        int r = i >> 5, c4 = i & 31;
        int node = base + r;
        float4 v = make_float4(0.f, 0.f, 0.f, 0.f);
        if (node < n) v = *(const float4*)(x + (size_t)node * 128 + c4 * 4);
        float* d = &xs[r * 129 + c4 * 4];
        d[0] = v.x; d[1] = v.y; d[2] = v.z; d[3] = v.w;
    }
    __syncthreads();
    const int nl = threadIdx.x & 63;
    const int node = base + nl;
    if (node >= n) return;
    float acc[32];
    #pragma unroll
    for (int c = 0; c < 32; ++c) acc[c] = 0.f;
    const float* xr = &xs[nl * 129];
    const float* K = (threadIdx.x < 64) ? K1 : K2;
    for (int k = 0; k < 128; ++k) {
        float xv = xr[k];
        #pragma unroll
        for (int c = 0; c < 32; ++c) acc[c] = fmaf(xv, K[k * 32 + c], acc[c]);
    }
    if (threadIdx.x < 64) {
        store_row_bf16(h + (size_t)node * 32, acc);
    } else {
        #pragma unroll
        for (int c = 0; c < 32; ++c) acc[c] += bias[c];
        float* out = p + (size_t)node * 32;
        #pragma unroll
        for (int c4 = 0; c4 < 8; ++c4)
            *(float4*)(out + c4 * 4) = make_float4(acc[c4*4], acc[c4*4+1], acc[c4*4+2], acc[c4*4+3]);
    }
}

__global__ __launch_bounds__(128) void gemm_f32_b(
    const float* __restrict__ x1,
    const float* __restrict__ K1, const float* __restrict__ K2,
    const float* __restrict__ bias,
    ushort* __restrict__ h, float* __restrict__ p, int n)
{
    __shared__ float xs[64 * 33];
    const int base = blockIdx.x * 64;
    for (int i = threadIdx.x; i < 64 * 8; i += 128) {
        int r = i >> 3, c4 = i & 7;
        int node = base + r;
        float4 a = make_float4(0.f, 0.f, 0.f, 0.f);
        if (node < n) a = *(const float4*)(x1 + (size_t)node * 32 + c4 * 4);
        float* d = &xs[r * 33 + c4 * 4];
        d[0] = a.x; d[1] = a.y; d[2] = a.z; d[3] = a.w;
    }
    __syncthreads();
    const int nl = threadIdx.x & 63;
    const int node = base + nl;
    if (node >= n) return;
    float acc[32];
    #pragma unroll
    for (int c = 0; c < 32; ++c) acc[c] = 0.f;
    const float* xr = &xs[nl * 33];
    const float* K = (threadIdx.x < 64) ? K1 : K2;
    for (int k = 0; k < 32; ++k) {
        float xv = xr[k];
        #pragma unroll
        for (int c = 0; c < 32; ++c) acc[c] = fmaf(xv, K[k * 32 + c], acc[c]);
    }
    if (threadIdx.x < 64) {
        store_row_bf16(h + (size_t)node * 32, acc);
    } else {
        #pragma unroll
        for (int c = 0; c < 32; ++c) acc[c] += bias[c];
        float* out = p + (size_t)node * 32;
        #pragma unroll
        for (int c4 = 0; c4 < 8; ++c4)
            *(float4*)(out + c4 * 4) = make_float4(acc[c4*4], acc[c4*4+1], acc[c4*4+2], acc[c4*4+3]);
    }
}

__global__ __launch_bounds__(256) void edge_scatter(
    const int* __restrict__ src, const int* __restrict__ dst,
    const float* __restrict__ w, const ushort* __restrict__ h,
    float* __restrict__ agg, int e)
{
    int t = blockIdx.x * 256 + threadIdx.x;
    int eid = t >> 3, q = t & 7;
    if (eid >= e) return;
    int s = src[eid];
    int d = dst[eid];
    float wv = w[eid];
    uint2 hv = *(const uint2*)(h + (size_t)s * 32 + q * 4);
    float f0, f1, f2, f3;
    bf16x4_decode(hv, f0, f1, f2, f3);
    float* ap = agg + (size_t)d * 32 + q * 4;
    unsafeAtomicAdd(ap + 0, f0 * wv);
    unsafeAtomicAdd(ap + 1, f1 * wv);
    unsafeAtomicAdd(ap + 2, f2 * wv);
    unsafeAtomicAdd(ap + 3, f3 * wv);
}

__global__ __launch_bounds__(256) void relu_add_kernel(
    const float* __restrict__ a, const float* __restrict__ b,
    float* __restrict__ o, size_t m)
{
    size_t i = (size_t)blockIdx.x * 256 + threadIdx.x;
    if (i < m) o[i] = fmaxf(a[i] + b[i], 0.f);
}

__global__ __launch_bounds__(256) void pool_kernel(
    const float* __restrict__ p, const float* __restrict__ agg,
    float* __restrict__ pooled, int n)
{
    const int ch = threadIdx.x & 31;
    const int r  = threadIdx.x >> 5;
    float acc = 0.f;
    for (int node = blockIdx.x * 8 + r; node < n; node += gridDim.x * 8) {
        size_t idx = (size_t)node * 32 + ch;
        acc += fmaxf(p[idx] + agg[idx], 0.f);
    }
    __shared__ float red[256];
    red[threadIdx.x] = acc;
    __syncthreads();
    if (threadIdx.x < 32) {
        float s = 0.f;
        #pragma unroll
        for (int i = 0; i < 8; ++i) s += red[i * 32 + ch];
        unsafeAtomicAdd(&pooled[ch], s);
    }
}

__global__ void dense_kernel(
    const float* __restrict__ pooled,
    const float* __restrict__ Wd1, const float* __restrict__ bd1,
    const float* __restrict__ Wd2, const float* __restrict__ bd2,
    float* __restrict__ out)
{
    int j = threadIdx.x;
    float t = 0.f;
    if (j < 24) {
        t = bd1[j];
        #pragma unroll
        for (int c = 0; c < 32; ++c) t = fmaf(pooled[c], Wd1[c * 24 + j], t);
        t *= Wd2[j];
    }
    #pragma unroll
    for (int off = 32; off > 0; off >>= 1) t += __shfl_down(t, off, 64);
    if (j == 0) out[0] = t + bd2[0];
}

extern "C" void kernel_launch(void* const* d_in, const int* in_sizes, int n_in,
                              void* d_out, int out_size, void* d_ws, size_t ws_size,
                              hipStream_t stream) {
    const float* x   = (const float*)d_in[0];
    const int*   esrc= (const int*)d_in[1];
    const int*   edst= (const int*)d_in[2];
    const float* ew  = (const float*)d_in[3];
    const float* K1a = (const float*)d_in[4];
    const float* K2a = (const float*)d_in[5];
    const float* ba  = (const float*)d_in[6];
    const float* K1b = (const float*)d_in[7];
    const float* K2b = (const float*)d_in[8];
    const float* bb  = (const float*)d_in[9];
    const float* Wd1 = (const float*)d_in[10];
    const float* bd1 = (const float*)d_in[11];
    const float* Wd2 = (const float*)d_in[12];
    const float* bd2 = (const float*)d_in[13];

    const int n = in_sizes[0] / 128;   // 100000
    const int e = in_sizes[1];         // 3200000
    const size_t nc = (size_t)n * 32;
    const int nb = (n + NPB - 1) / NPB;            // 391
    const int nruns = (e + CHUNK - 1) / CHUNK;     // 391

    // ws layout:
    //   epack [e] ull                 (persists through gathers)
    //   etmp  [e] ull  -> reused as A_bf16[nc] + B_f32[nc] after sort_buckets
    //   Cg    [nc] f32  (holds bf16 x1, needs only nc*2)
    //   pooled [32] f32
    //   row   [n+1] int
    //   bucket_cnt [nb] int | bucket_base [nb+1] int
    //   runoff [nruns*(nb+1)] int
    //   Kca [64*128] bf16 | Kcb [64*32] bf16
    const size_t ab_bytes = nc * 2 + nc * 4;   // A bf16 + B f32
    const size_t etmp_bytes = ((size_t)e * 8 > ab_bytes) ? (size_t)e * 8 : ab_bytes;
    const size_t need = (size_t)e * 8 + etmp_bytes + nc * 4 + 32 * 4
                      + (size_t)(n + 1) * 4 + (size_t)nb * 4 + (size_t)(nb + 1) * 4
                      + (size_t)nruns * (nb + 1) * 4
                      + (8192 + 2048) * 2 + 256;

    const int gemm_blocks   = (n + 63) / 64;
    const int gather_blocks = (n + 31) / 32;

    if (ws_size >= need && nb <= NBMAX) {
        char* wp = (char*)d_ws;
        ull* epack = (ull*)wp;                wp += (size_t)e * 8;
        ull* etmp  = (ull*)wp;
        ushort* A = (ushort*)etmp;            // bf16 h, aliases etmp after sort
        float* B = (float*)(A + nc);          wp += etmp_bytes;
        ushort* x1b = (ushort*)wp;            wp += nc * 4;   // bf16 x1 (uses half)
        float* pooled = (float*)wp;           wp += 32 * 4;
        int* row = (int*)wp;                  wp += (size_t)(n + 1) * 4;
        int* bucket_cnt = (int*)wp;           wp += (size_t)nb * 4;
        int* bucket_base = (int*)wp;          wp += (size_t)(nb + 1) * 4;
        int* runoff = (int*)wp;               wp += (size_t)nruns * (nb + 1) * 4;
        ushort* Kca = (ushort*)wp;            wp += 8192 * 2;
        ushort* Kcb = (ushort*)wp;

        hipMemsetAsync(bucket_cnt, 0, (size_t)nb * 4, stream);
        hipMemsetAsync(pooled, 0, 32 * 4, stream);

        prep_weights<<<32, 256, 0, stream>>>(K1a, K2a, K1b, K2b, Kca, Kcb);
        build_runs_kernel<<<nruns, 512, 0, stream>>>(esrc, edst, ew, etmp, runoff,
                                                     bucket_cnt, e, nruns, nb);
        bucket_scan_kernel<<<1, 512, 0, stream>>>(bucket_cnt, bucket_base, nb, e);
        sort_buckets_kernel<<<nb, 512, 0, stream>>>(etmp, runoff, bucket_base,
                                                    epack, row, n, e, nruns, nb);
        // etmp is dead now; its storage becomes A (bf16 h), B (f32 p).
        gemm_mfma_a<<<gemm_blocks, 256, 0, stream>>>(x, Kca, ba, A, B, n);
        gather_x1_kernel<<<gather_blocks, 256, 0, stream>>>(row, epack, A, B, x1b, n);
        gemm_mfma_b<<<gemm_blocks, 256, 0, stream>>>(x1b, Kcb, bb, A, B, n);
        gather_pool_kernel<<<gather_blocks, 256, 0, stream>>>(row, epack, A, B, pooled, n);
        dense_kernel<<<1, 64, 0, stream>>>(pooled, Wd1, bd1, Wd2, bd2, (float*)d_out);
    } else {
        // fallback: atomic scatter path (f32 VALU GEMMs)
        ushort* A     = (ushort*)d_ws;             // bf16 h
        float* B      = (float*)(A + 2 * nc);
        float* Cg     = B + nc;
        float* pooled = Cg + nc;
        const int edge_blocks_8 = (int)(((long long)e * 8 + 255) / 256);

        hipMemsetAsync(Cg, 0, nc * 4, stream);
        gemm_f32_a<<<gemm_blocks, 128, 0, stream>>>(x, K1a, K2a, ba, A, B, n);
        edge_scatter<<<edge_blocks_8, 256, 0, stream>>>(esrc, edst, ew, A, Cg, e);
        relu_add_kernel<<<(int)((nc + 255) / 256), 256, 0, stream>>>(B, Cg, B, nc);
        gemm_f32_b<<<gemm_blocks, 128, 0, stream>>>(B, K1b, K2b, bb, A, Cg, n);
        hipMemsetAsync(B, 0, nc * 4, stream);
        edge_scatter<<<edge_blocks_8, 256, 0, stream>>>(esrc, edst, ew, A, B, e);
        hipMemsetAsync(pooled, 0, 32 * 4, stream);
        pool_kernel<<<1024, 256, 0, stream>>>(Cg, B, pooled, n);
        dense_kernel<<<1, 64, 0, stream>>>(pooled, Wd1, bd1, Wd2, bd2, (float*)d_out);
    }
}

// Round 8
// 217.592 us; speedup vs baseline: 7.0367x; 1.0294x over previous
//
#include <hip/hip_runtime.h>
#include <hip/hip_bf16.h>

typedef unsigned long long ull;
typedef unsigned int uint;
typedef unsigned short ushort;

using bf16x8 = __attribute__((ext_vector_type(8))) short;
using f32x4  = __attribute__((ext_vector_type(4))) float;

// Problem constants: N=100000 nodes, E=3200000 edges, F=128, C=32, H=24
//
// Pipeline:
//   0. prep_weights: [K1|K2] -> bf16, transposed [col][k]
//   1. build_runs / bucket_scan / sort_buckets: dst-sorted epack + CSR row[]
//   2. gemm_mfma_a:  h_a = bf16(x@K1a), p_a = x@K2a + ba   (MFMA 16x16x32)
//   3. gather_x1:    x1 = bf16(relu(csr_gather(h_a) + p_a))  [unroll 8 MLP]
//   4. gemm_mfma_b:  h_b = bf16(x1@K1b), p_b = x1@K2b + bb (MFMA, K=32)
//   5. gather_pool:  pooled += relu(csr_gather(h_b) + p_b)
//   6. dense epilogue
//
// record: low = src | (dst&255)<<20 ; high = f32 bits of w   (src < 2^20)

#define CHUNK    8192
#define NPB      256
#define NBMAX    512
#define STAGECAP 9216   // 72 KB

__device__ __forceinline__ ushort f2bf(float f) {
    __hip_bfloat16 b = __float2bfloat16(f);
    return *reinterpret_cast<ushort*>(&b);
}
__device__ __forceinline__ uint pack2(float a, float b) {
    return (uint)f2bf(a) | ((uint)f2bf(b) << 16);
}
__device__ __forceinline__ void bf16x4_decode(uint2 hv, float& f0, float& f1,
                                              float& f2, float& f3) {
    f0 = __uint_as_float(hv.x << 16);
    f1 = __uint_as_float(hv.x & 0xFFFF0000u);
    f2 = __uint_as_float(hv.y << 16);
    f3 = __uint_as_float(hv.y & 0xFFFF0000u);
}

// ---------------------------------------------------------------------------
// Phase 0: weight prep. Kca[col][k] (64x128), Kcb[col][k] (64x32), bf16.
// ---------------------------------------------------------------------------
__global__ __launch_bounds__(256) void prep_weights(
    const float* __restrict__ K1a, const float* __restrict__ K2a,
    const float* __restrict__ K1b, const float* __restrict__ K2b,
    ushort* __restrict__ Kca, ushort* __restrict__ Kcb)
{
    int t = blockIdx.x * 256 + threadIdx.x;
    if (t < 8192) {
        int col = t >> 7, k = t & 127;
        float v = (col < 32) ? K1a[k * 32 + col] : K2a[k * 32 + col - 32];
        Kca[col * 128 + k] = f2bf(v);
    }
    if (t < 2048) {
        int col = t >> 5, k = t & 31;
        float v = (col < 32) ? K1b[k * 32 + col] : K2b[k * 32 + col - 32];
        Kcb[col * 32 + k] = f2bf(v);
    }
}

// ---------------------------------------------------------------------------
// Phase 1: LDS-staged counting sort of each 8192-edge chunk by bucket.
// ---------------------------------------------------------------------------
__global__ __launch_bounds__(512) void build_runs_kernel(
    const int* __restrict__ src, const int* __restrict__ dst,
    const float* __restrict__ w,
    ull* __restrict__ etmp, int* __restrict__ runoff,
    int* __restrict__ bucket_cnt, int e, int nruns, int nb)
{
    __shared__ ull stage[CHUNK];      // 64 KB
    __shared__ int hist[NBMAX];
    __shared__ int scn[NBMAX];
    const int r = blockIdx.x, tid = threadIdx.x;
    const int base = r * CHUNK;
    const int cnt = min(CHUNK, e - base);

    hist[tid] = 0;
    __syncthreads();

    int dreg[CHUNK / 512];
    #pragma unroll
    for (int k = 0; k < CHUNK / 512; ++k) {
        int i = tid + k * 512;
        int d = (i < cnt) ? dst[base + i] : -1;
        dreg[k] = d;
        if (d >= 0) atomicAdd(&hist[d >> 8], 1);
    }
    __syncthreads();

    int v = hist[tid];
    scn[tid] = v;
    __syncthreads();
    for (int off = 1; off < NBMAX; off <<= 1) {
        int u = (tid >= off) ? scn[tid - off] : 0;
        __syncthreads();
        scn[tid] += u;
        __syncthreads();
    }
    const int ex = scn[tid] - v;
    if (tid < nb && v) atomicAdd(&bucket_cnt[tid], v);
    hist[tid] = ex;                   // becomes cursor
    if (tid <= nb) runoff[(size_t)r * (nb + 1) + tid] = base + ex;
    __syncthreads();

    #pragma unroll
    for (int k = 0; k < CHUNK / 512; ++k) {
        int i = tid + k * 512;
        int d = dreg[k];
        if (d >= 0) {
            int pos = atomicAdd(&hist[d >> 8], 1);
            unsigned lo = (unsigned)src[base + i] | ((unsigned)(d & 255) << 20);
            stage[pos] = (ull)lo | ((ull)__float_as_uint(w[base + i]) << 32);
        }
    }
    __syncthreads();

    for (int i = tid; i < cnt; i += 512) etmp[base + i] = stage[i];
}

__global__ __launch_bounds__(512) void bucket_scan_kernel(
    const int* __restrict__ cnt, int* __restrict__ basep, int nb, int e)
{
    __shared__ int s[512];
    int t = threadIdx.x;
    int v = (t < nb) ? cnt[t] : 0;
    s[t] = v; __syncthreads();
    for (int off = 1; off < 512; off <<= 1) {
        int u = (t >= off) ? s[t - off] : 0;
        __syncthreads(); s[t] += u; __syncthreads();
    }
    if (t < nb) basep[t] = s[t] - v;
    if (t == 0) basep[nb] = e;
}

// ---------------------------------------------------------------------------
// Phase 3: fine sort per bucket (LDS stage, coalesced copy-out).
// ---------------------------------------------------------------------------
__global__ __launch_bounds__(512) void sort_buckets_kernel(
    const ull* __restrict__ etmp, const int* __restrict__ runoff,
    const int* __restrict__ bbase,
    ull* __restrict__ epack, int* __restrict__ row,
    int n, int e, int nruns, int nb)
{
    __shared__ ull stage[STAGECAP];   // 72 KB
    __shared__ int hist[NPB];
    __shared__ int scn[NPB];
    __shared__ int cur[NPB];
    const int b = blockIdx.x, tid = threadIdx.x;
    const int base0 = bbase[b];
    const int cnt = bbase[b + 1] - base0;

    if (tid < NPB) hist[tid] = 0;
    __syncthreads();

    const int stream = tid >> 3, sub = tid & 7;   // 64 streams x 8 lanes
    const int* rs = runoff;

    for (int r = stream; r < nruns; r += 64) {
        int s0 = rs[(size_t)r * (nb + 1) + b];
        int s1 = rs[(size_t)r * (nb + 1) + b + 1];
        for (int i = s0 + sub; i < s1; i += 8)
            atomicAdd(&hist[(int)((etmp[i] >> 20) & 255u)], 1);
    }
    __syncthreads();

    int v = (tid < NPB) ? hist[tid] : 0;
    if (tid < NPB) scn[tid] = v;
    __syncthreads();
    for (int off = 1; off < NPB; off <<= 1) {
        int u = (tid >= off && tid < NPB) ? scn[tid - off] : 0;
        __syncthreads();
        if (tid < NPB) scn[tid] += u;
        __syncthreads();
    }
    if (tid < NPB) {
        int ex = scn[tid] - v;
        cur[tid] = ex;
        int node = b * NPB + tid;
        if (node < n) row[node] = base0 + ex;
    }
    if (b == nb - 1 && tid == 0) row[n] = e;
    __syncthreads();

    if (cnt <= STAGECAP) {
        for (int r = stream; r < nruns; r += 64) {
            int s0 = rs[(size_t)r * (nb + 1) + b];
            int s1 = rs[(size_t)r * (nb + 1) + b + 1];
            for (int i = s0 + sub; i < s1; i += 8) {
                ull pk = etmp[i];
                int pos = atomicAdd(&cur[(int)((pk >> 20) & 255u)], 1);
                stage[pos] = pk;
            }
        }
        __syncthreads();
        for (int i = tid; i < cnt; i += 512) epack[(size_t)base0 + i] = stage[i];
    } else {
        for (int r = stream; r < nruns; r += 64) {
            int s0 = rs[(size_t)r * (nb + 1) + b];
            int s1 = rs[(size_t)r * (nb + 1) + b + 1];
            for (int i = s0 + sub; i < s1; i += 8) {
                ull pk = etmp[i];
                int pos = atomicAdd(&cur[(int)((pk >> 20) & 255u)], 1);
                epack[(size_t)base0 + pos] = pk;
            }
        }
    }
}

// ---------------------------------------------------------------------------
// MFMA dual GEMM layer a: [64 nodes] x [128 K] @ [128][64 cols = K1a|K2a].
// ---------------------------------------------------------------------------
__global__ __launch_bounds__(256) void gemm_mfma_a(
    const float* __restrict__ x, const ushort* __restrict__ Kca,
    const float* __restrict__ bias,
    ushort* __restrict__ h, float* __restrict__ p, int n)
{
    __shared__ ushort xs[64 * 136];   // 17408 B
    const int tid = threadIdx.x;
    const int base = blockIdx.x * 64;

    for (int idx = tid; idx < 64 * 16; idx += 256) {
        int nl = idx >> 4, c8 = idx & 15;
        int node = base + nl;
        float4 v0 = make_float4(0.f, 0.f, 0.f, 0.f);
        float4 v1 = v0;
        if (node < n) {
            const float* xp = x + (size_t)node * 128 + c8 * 8;
            v0 = *(const float4*)xp;
            v1 = *(const float4*)(xp + 4);
        }
        uint4 u;
        u.x = pack2(v0.x, v0.y); u.y = pack2(v0.z, v0.w);
        u.z = pack2(v1.x, v1.y); u.w = pack2(v1.z, v1.w);
        *(uint4*)&xs[nl * 136 + c8 * 8] = u;
    }
    __syncthreads();

    const int lane = tid & 63, w = tid >> 6;
    const int r15 = lane & 15, g = lane >> 4;
    const int nbase = w * 16;

    f32x4 acc[4] = {{0.f,0.f,0.f,0.f},{0.f,0.f,0.f,0.f},
                    {0.f,0.f,0.f,0.f},{0.f,0.f,0.f,0.f}};

    #pragma unroll
    for (int kk = 0; kk < 4; ++kk) {
        bf16x8 af = *(const bf16x8*)&xs[(nbase + r15) * 136 + kk * 32 + g * 8];
        #pragma unroll
        for (int t = 0; t < 4; ++t) {
            bf16x8 bfr = *(const bf16x8*)&Kca[(size_t)(t * 16 + r15) * 128 + kk * 32 + g * 8];
            acc[t] = __builtin_amdgcn_mfma_f32_16x16x32_bf16(af, bfr, acc[t], 0, 0, 0);
        }
    }

    #pragma unroll
    for (int t = 0; t < 4; ++t) {
        int col = t * 16 + r15;
        float bv = (col >= 32) ? bias[col - 32] : 0.f;
        #pragma unroll
        for (int i = 0; i < 4; ++i) {
            int node = base + nbase + g * 4 + i;
            if (node < n) {
                float v = acc[t][i];
                if (col < 32) h[(size_t)node * 32 + col] = f2bf(v);
                else          p[(size_t)node * 32 + col - 32] = v + bv;
            }
        }
    }
}

// ---------------------------------------------------------------------------
// MFMA dual GEMM layer b: [64 nodes] x [32 K] @ [32][64 cols]. K=32 = 1 step.
// ---------------------------------------------------------------------------
__global__ __launch_bounds__(256) void gemm_mfma_b(
    const ushort* __restrict__ x1, const ushort* __restrict__ Kcb,
    const float* __restrict__ bias,
    ushort* __restrict__ h, float* __restrict__ p, int n)
{
    __shared__ ushort xs[64 * 40];    // 5120 B
    const int tid = threadIdx.x;
    const int base = blockIdx.x * 64;

    {
        int nl = tid >> 2, c8 = tid & 3;
        int node = base + nl;
        uint4 u = make_uint4(0u, 0u, 0u, 0u);
        if (node < n) u = *(const uint4*)(x1 + (size_t)node * 32 + c8 * 8);
        *(uint4*)&xs[nl * 40 + c8 * 8] = u;
    }
    __syncthreads();

    const int lane = tid & 63, w = tid >> 6;
    const int r15 = lane & 15, g = lane >> 4;
    const int nbase = w * 16;

    f32x4 acc[4] = {{0.f,0.f,0.f,0.f},{0.f,0.f,0.f,0.f},
                    {0.f,0.f,0.f,0.f},{0.f,0.f,0.f,0.f}};

    bf16x8 af = *(const bf16x8*)&xs[(nbase + r15) * 40 + g * 8];
    #pragma unroll
    for (int t = 0; t < 4; ++t) {
        bf16x8 bfr = *(const bf16x8*)&Kcb[(size_t)(t * 16 + r15) * 32 + g * 8];
        acc[t] = __builtin_amdgcn_mfma_f32_16x16x32_bf16(af, bfr, acc[t], 0, 0, 0);
    }

    #pragma unroll
    for (int t = 0; t < 4; ++t) {
        int col = t * 16 + r15;
        float bv = (col >= 32) ? bias[col - 32] : 0.f;
        #pragma unroll
        for (int i = 0; i < 4; ++i) {
            int node = base + nbase + g * 4 + i;
            if (node < n) {
                float v = acc[t][i];
                if (col < 32) h[(size_t)node * 32 + col] = f2bf(v);
                else          p[(size_t)node * 32 + col - 32] = v + bv;
            }
        }
    }
}

// ---------------------------------------------------------------------------
// CSR gather core: 8 threads/node, bf16 h rows (64 B/edge), 8-way unroll
// for deep MLP (8 independent line-fetches in flight per thread).
// ---------------------------------------------------------------------------
__device__ __forceinline__ float4 gather_node(
    const int* __restrict__ row, const ull* __restrict__ epack,
    const ushort* __restrict__ h, int node, int q)
{
    int r0 = row[node], r1 = row[node + 1];
    float4 a = make_float4(0.f, 0.f, 0.f, 0.f);
    float4 b = make_float4(0.f, 0.f, 0.f, 0.f);
    int i = r0;
    for (; i + 7 < r1; i += 8) {
        ull pk[8];
        uint2 hv[8];
        #pragma unroll
        for (int u = 0; u < 8; ++u) pk[u] = epack[i + u];
        #pragma unroll
        for (int u = 0; u < 8; ++u)
            hv[u] = *(const uint2*)(h + (size_t)(pk[u] & 0xFFFFFu) * 32 + q * 4);
        #pragma unroll
        for (int u = 0; u < 8; ++u) {
            float wv = __uint_as_float((uint)(pk[u] >> 32));
            float f0, f1, f2, f3;
            bf16x4_decode(hv[u], f0, f1, f2, f3);
            if (u & 1) {
                b.x = fmaf(wv, f0, b.x); b.y = fmaf(wv, f1, b.y);
                b.z = fmaf(wv, f2, b.z); b.w = fmaf(wv, f3, b.w);
            } else {
                a.x = fmaf(wv, f0, a.x); a.y = fmaf(wv, f1, a.y);
                a.z = fmaf(wv, f2, a.z); a.w = fmaf(wv, f3, a.w);
            }
        }
    }
    for (; i + 3 < r1; i += 4) {
        ull pk[4];
        uint2 hv[4];
        #pragma unroll
        for (int u = 0; u < 4; ++u) pk[u] = epack[i + u];
        #pragma unroll
        for (int u = 0; u < 4; ++u)
            hv[u] = *(const uint2*)(h + (size_t)(pk[u] & 0xFFFFFu) * 32 + q * 4);
        #pragma unroll
        for (int u = 0; u < 4; ++u) {
            float wv = __uint_as_float((uint)(pk[u] >> 32));
            float f0, f1, f2, f3;
            bf16x4_decode(hv[u], f0, f1, f2, f3);
            if (u & 1) {
                b.x = fmaf(wv, f0, b.x); b.y = fmaf(wv, f1, b.y);
                b.z = fmaf(wv, f2, b.z); b.w = fmaf(wv, f3, b.w);
            } else {
                a.x = fmaf(wv, f0, a.x); a.y = fmaf(wv, f1, a.y);
                a.z = fmaf(wv, f2, a.z); a.w = fmaf(wv, f3, a.w);
            }
        }
    }
    for (; i < r1; ++i) {
        ull p0 = epack[i];
        uint2 h0 = *(const uint2*)(h + (size_t)(p0 & 0xFFFFFu) * 32 + q * 4);
        float w0 = __uint_as_float((uint)(p0 >> 32));
        float f0, f1, f2, f3;
        bf16x4_decode(h0, f0, f1, f2, f3);
        a.x = fmaf(w0, f0, a.x); a.y = fmaf(w0, f1, a.y);
        a.z = fmaf(w0, f2, a.z); a.w = fmaf(w0, f3, a.w);
    }
    a.x += b.x; a.y += b.y; a.z += b.z; a.w += b.w;
    return a;
}

// x1 = bf16(relu(agg + p)), coalesced uint2 stores.
__global__ __launch_bounds__(256) void gather_x1_kernel(
    const int* __restrict__ row, const ull* __restrict__ epack,
    const ushort* __restrict__ h, const float* __restrict__ p,
    ushort* __restrict__ x1, int n)
{
    const int q = threadIdx.x & 7;
    const int node = blockIdx.x * 32 + (threadIdx.x >> 3);
    if (node >= n) return;
    float4 acc = gather_node(row, epack, h, node, q);
    const float4 pv = *(const float4*)(p + (size_t)node * 32 + q * 4);
    float4 o;
    o.x = fmaxf(acc.x + pv.x, 0.f);
    o.y = fmaxf(acc.y + pv.y, 0.f);
    o.z = fmaxf(acc.z + pv.z, 0.f);
    o.w = fmaxf(acc.w + pv.w, 0.f);
    uint2 u;
    u.x = pack2(o.x, o.y);
    u.y = pack2(o.z, o.w);
    *(uint2*)(x1 + (size_t)node * 32 + q * 4) = u;
}

__global__ __launch_bounds__(256) void gather_pool_kernel(
    const int* __restrict__ row, const ull* __restrict__ epack,
    const ushort* __restrict__ h, const float* __restrict__ p,
    float* __restrict__ pooled, int n)
{
    const int q = threadIdx.x & 7;
    const int node = blockIdx.x * 32 + (threadIdx.x >> 3);

    float4 o = make_float4(0.f, 0.f, 0.f, 0.f);
    if (node < n) {
        float4 acc = gather_node(row, epack, h, node, q);
        const float4 pv = *(const float4*)(p + (size_t)node * 32 + q * 4);
        o.x = fmaxf(acc.x + pv.x, 0.f);
        o.y = fmaxf(acc.y + pv.y, 0.f);
        o.z = fmaxf(acc.z + pv.z, 0.f);
        o.w = fmaxf(acc.w + pv.w, 0.f);
    }
    __shared__ float red[256][4];
    red[threadIdx.x][0] = o.x; red[threadIdx.x][1] = o.y;
    red[threadIdx.x][2] = o.z; red[threadIdx.x][3] = o.w;
    __syncthreads();
    if (threadIdx.x < 32) {
        const int c = threadIdx.x;
        const int cq = c >> 2, cj = c & 3;
        float s = 0.f;
        #pragma unroll
        for (int l = 0; l < 32; ++l) s += red[l * 8 + cq][cj];
        unsafeAtomicAdd(&pooled[c], s);
    }
}

// ---------------------------------------------------------------------------
// Fallback path kernels (f32 VALU GEMMs, atomic scatter) — only if ws small.
// ---------------------------------------------------------------------------
__device__ __forceinline__ void store_row_bf16(ushort* out, const float* acc) {
    uint u[16];
    #pragma unroll
    for (int k = 0; k < 16; ++k) u[k] = pack2(acc[2 * k], acc[2 * k + 1]);
    uint4* o = (uint4*)out;
    o[0] = make_uint4(u[0], u[1], u[2], u[3]);
    o[1] = make_uint4(u[4], u[5], u[6], u[7]);
    o[2] = make_uint4(u[8], u[9], u[10], u[11]);
    o[3] = make_uint4(u[12], u[13], u[14], u[15]);
}

__global__ __launch_bounds__(128) void gemm_f32_a(
    const float* __restrict__ x, const float* __restrict__ K1,
    const float* __restrict__ K2, const float* __restrict__ bias,
    ushort* __restrict__ h, float* __restrict__ p, int n)
{
    __shared__ float xs[64 * 129];
    const int base = blockIdx.x * 64;
    for (int i = threadIdx.x; i < 64 * 32; i += 128) {
        int r = i >> 5, c4 = i & 31;
        int node = base + r;
        float4 v = make_float4(0.f, 0.f, 0.f, 0.f);
        if (node < n) v = *(const float4*)(x + (size_t)node * 128 + c4 * 4);
        float* d = &xs[r * 129 + c4 * 4];
        d[0] = v.x; d[1] = v.y; d[2] = v.z; d[3] = v.w;
    }
    __syncthreads();
    const int nl = threadIdx.x & 63;
    const int node = base + nl;
    if (node >= n) return;
    float acc[32];
    #pragma unroll
    for (int c = 0; c < 32; ++c) acc[c] = 0.f;
    const float* xr = &xs[nl * 129];
    const float* K = (threadIdx.x < 64) ? K1 : K2;
    for (int k = 0; k < 128; ++k) {
        float xv = xr[k];
        #pragma unroll
        for (int c = 0; c < 32; ++c) acc[c] = fmaf(xv, K[k * 32 + c], acc[c]);
    }
    if (threadIdx.x < 64) {
        store_row_bf16(h + (size_t)node * 32, acc);
    } else {
        #pragma unroll
        for (int c = 0; c < 32; ++c) acc[c] += bias[c];
        float* out = p + (size_t)node * 32;
        #pragma unroll
        for (int c4 = 0; c4 < 8; ++c4)
            *(float4*)(out + c4 * 4) = make_float4(acc[c4*4], acc[c4*4+1], acc[c4*4+2], acc[c4*4+3]);
    }
}

__global__ __launch_bounds__(128) void gemm_f32_b(
    const float* __restrict__ x1,
    const float* __restrict__ K1, const float* __restrict__ K2,
    const float* __restrict__ bias,
    ushort* __restrict__ h, float* __restrict__ p, int n)
{
    __shared__ float xs[64 * 33];
    const int base = blockIdx.x * 64;
    for (int i = threadIdx.x; i < 64 * 8; i += 128) {
        int r = i >> 3, c4 = i & 7;
        int node = base + r;
        float4 a = make_float4(0.f, 0.f, 0.f, 0.f);
        if (node < n) a = *(const float4*)(x1 + (size_t)node * 32 + c4 * 4);
        float* d = &xs[r * 33 + c4 * 4];
        d[0] = a.x; d[1] = a.y; d[2] = a.z; d[3] = a.w;
    }
    __syncthreads();
    const int nl = threadIdx.x & 63;
    const int node = base + nl;
    if (node >= n) return;
    float acc[32];
    #pragma unroll
    for (int c = 0; c < 32; ++c) acc[c] = 0.f;
    const float* xr = &xs[nl * 33];
    const float* K = (threadIdx.x < 64) ? K1 : K2;
    for (int k = 0; k < 32; ++k) {
        float xv = xr[k];
        #pragma unroll
        for (int c = 0; c < 32; ++c) acc[c] = fmaf(xv, K[k * 32 + c], acc[c]);
    }
    if (threadIdx.x < 64) {
        store_row_bf16(h + (size_t)node * 32, acc);
    } else {
        #pragma unroll
        for (int c = 0; c < 32; ++c) acc[c] += bias[c];
        float* out = p + (size_t)node * 32;
        #pragma unroll
        for (int c4 = 0; c4 < 8; ++c4)
            *(float4*)(out + c4 * 4) = make_float4(acc[c4*4], acc[c4*4+1], acc[c4*4+2], acc[c4*4+3]);
    }
}

__global__ __launch_bounds__(256) void edge_scatter(
    const int* __restrict__ src, const int* __restrict__ dst,
    const float* __restrict__ w, const ushort* __restrict__ h,
    float* __restrict__ agg, int e)
{
    int t = blockIdx.x * 256 + threadIdx.x;
    int eid = t >> 3, q = t & 7;
    if (eid >= e) return;
    int s = src[eid];
    int d = dst[eid];
    float wv = w[eid];
    uint2 hv = *(const uint2*)(h + (size_t)s * 32 + q * 4);
    float f0, f1, f2, f3;
    bf16x4_decode(hv, f0, f1, f2, f3);
    float* ap = agg + (size_t)d * 32 + q * 4;
    unsafeAtomicAdd(ap + 0, f0 * wv);
    unsafeAtomicAdd(ap + 1, f1 * wv);
    unsafeAtomicAdd(ap + 2, f2 * wv);
    unsafeAtomicAdd(ap + 3, f3 * wv);
}

__global__ __launch_bounds__(256) void relu_add_kernel(
    const float* __restrict__ a, const float* __restrict__ b,
    float* __restrict__ o, size_t m)
{
    size_t i = (size_t)blockIdx.x * 256 + threadIdx.x;
    if (i < m) o[i] = fmaxf(a[i] + b[i], 0.f);
}

__global__ __launch_bounds__(256) void pool_kernel(
    const float* __restrict__ p, const float* __restrict__ agg,
    float* __restrict__ pooled, int n)
{
    const int ch = threadIdx.x & 31;
    const int r  = threadIdx.x >> 5;
    float acc = 0.f;
    for (int node = blockIdx.x * 8 + r; node < n; node += gridDim.x * 8) {
        size_t idx = (size_t)node * 32 + ch;
        acc += fmaxf(p[idx] + agg[idx], 0.f);
    }
    __shared__ float red[256];
    red[threadIdx.x] = acc;
    __syncthreads();
    if (threadIdx.x < 32) {
        float s = 0.f;
        #pragma unroll
        for (int i = 0; i < 8; ++i) s += red[i * 32 + ch];
        unsafeAtomicAdd(&pooled[ch], s);
    }
}

__global__ void dense_kernel(
    const float* __restrict__ pooled,
    const float* __restrict__ Wd1, const float* __restrict__ bd1,
    const float* __restrict__ Wd2, const float* __restrict__ bd2,
    float* __restrict__ out)
{
    int j = threadIdx.x;
    float t = 0.f;
    if (j < 24) {
        t = bd1[j];
        #pragma unroll
        for (int c = 0; c < 32; ++c) t = fmaf(pooled[c], Wd1[c * 24 + j], t);
        t *= Wd2[j];
    }
    #pragma unroll
    for (int off = 32; off > 0; off >>= 1) t += __shfl_down(t, off, 64);
    if (j == 0) out[0] = t + bd2[0];
}

extern "C" void kernel_launch(void* const* d_in, const int* in_sizes, int n_in,
                              void* d_out, int out_size, void* d_ws, size_t ws_size,
                              hipStream_t stream) {
    const float* x   = (const float*)d_in[0];
    const int*   esrc= (const int*)d_in[1];
    const int*   edst= (const int*)d_in[2];
    const float* ew  = (const float*)d_in[3];
    const float* K1a = (const float*)d_in[4];
    const float* K2a = (const float*)d_in[5];
    const float* ba  = (const float*)d_in[6];
    const float* K1b = (const float*)d_in[7];
    const float* K2b = (const float*)d_in[8];
    const float* bb  = (const float*)d_in[9];
    const float* Wd1 = (const float*)d_in[10];
    const float* bd1 = (const float*)d_in[11];
    const float* Wd2 = (const float*)d_in[12];
    const float* bd2 = (const float*)d_in[13];

    const int n = in_sizes[0] / 128;   // 100000
    const int e = in_sizes[1];         // 3200000
    const size_t nc = (size_t)n * 32;
    const int nb = (n + NPB - 1) / NPB;            // 391
    const int nruns = (e + CHUNK - 1) / CHUNK;     // 391

    const size_t ab_bytes = nc * 2 + nc * 4;   // A bf16 + B f32
    const size_t etmp_bytes = ((size_t)e * 8 > ab_bytes) ? (size_t)e * 8 : ab_bytes;
    const size_t need = (size_t)e * 8 + etmp_bytes + nc * 4 + 32 * 4
                      + (size_t)(n + 1) * 4 + (size_t)nb * 4 + (size_t)(nb + 1) * 4
                      + (size_t)nruns * (nb + 1) * 4
                      + (8192 + 2048) * 2 + 256;

    const int gemm_blocks   = (n + 63) / 64;
    const int gather_blocks = (n + 31) / 32;

    if (ws_size >= need && nb <= NBMAX) {
        char* wp = (char*)d_ws;
        ull* epack = (ull*)wp;                wp += (size_t)e * 8;
        ull* etmp  = (ull*)wp;
        ushort* A = (ushort*)etmp;            // bf16 h, aliases etmp after sort
        float* B = (float*)(A + nc);          wp += etmp_bytes;
        ushort* x1b = (ushort*)wp;            wp += nc * 4;   // bf16 x1 (uses half)
        float* pooled = (float*)wp;           wp += 32 * 4;
        int* row = (int*)wp;                  wp += (size_t)(n + 1) * 4;
        int* bucket_cnt = (int*)wp;           wp += (size_t)nb * 4;
        int* bucket_base = (int*)wp;          wp += (size_t)(nb + 1) * 4;
        int* runoff = (int*)wp;               wp += (size_t)nruns * (nb + 1) * 4;
        ushort* Kca = (ushort*)wp;            wp += 8192 * 2;
        ushort* Kcb = (ushort*)wp;

        hipMemsetAsync(bucket_cnt, 0, (size_t)nb * 4, stream);
        hipMemsetAsync(pooled, 0, 32 * 4, stream);

        prep_weights<<<32, 256, 0, stream>>>(K1a, K2a, K1b, K2b, Kca, Kcb);
        build_runs_kernel<<<nruns, 512, 0, stream>>>(esrc, edst, ew, etmp, runoff,
                                                     bucket_cnt, e, nruns, nb);
        bucket_scan_kernel<<<1, 512, 0, stream>>>(bucket_cnt, bucket_base, nb, e);
        sort_buckets_kernel<<<nb, 512, 0, stream>>>(etmp, runoff, bucket_base,
                                                    epack, row, n, e, nruns, nb);
        // etmp is dead now; its storage becomes A (bf16 h), B (f32 p).
        gemm_mfma_a<<<gemm_blocks, 256, 0, stream>>>(x, Kca, ba, A, B, n);
        gather_x1_kernel<<<gather_blocks, 256, 0, stream>>>(row, epack, A, B, x1b, n);
        gemm_mfma_b<<<gemm_blocks, 256, 0, stream>>>(x1b, Kcb, bb, A, B, n);
        gather_pool_kernel<<<gather_blocks, 256, 0, stream>>>(row, epack, A, B, pooled, n);
        dense_kernel<<<1, 64, 0, stream>>>(pooled, Wd1, bd1, Wd2, bd2, (float*)d_out);
    } else {
        // fallback: atomic scatter path (f32 VALU GEMMs)
        ushort* A     = (ushort*)d_ws;             // bf16 h
        float* B      = (float*)(A + 2 * nc);
        float* Cg     = B + nc;
        float* pooled = Cg + nc;
        const int edge_blocks_8 = (int)(((long long)e * 8 + 255) / 256);

        hipMemsetAsync(Cg, 0, nc * 4, stream);
        gemm_f32_a<<<gemm_blocks, 128, 0, stream>>>(x, K1a, K2a, ba, A, B, n);
        edge_scatter<<<edge_blocks_8, 256, 0, stream>>>(esrc, edst, ew, A, Cg, e);
        relu_add_kernel<<<(int)((nc + 255) / 256), 256, 0, stream>>>(B, Cg, B, nc);
        gemm_f32_b<<<gemm_blocks, 128, 0, stream>>>(B, K1b, K2b, bb, A, Cg, n);
        hipMemsetAsync(B, 0, nc * 4, stream);
        edge_scatter<<<edge_blocks_8, 256, 0, stream>>>(esrc, edst, ew, A, B, e);
        hipMemsetAsync(pooled, 0, 32 * 4, stream);
        pool_kernel<<<1024, 256, 0, stream>>>(Cg, B, pooled, n);
        dense_kernel<<<1, 64, 0, stream>>>(pooled, Wd1, bd1, Wd2, bd2, (float*)d_out);
    }
}